// Round 9
// baseline (1240.038 us; speedup 1.0000x reference)
//
#include <hip/hip_runtime.h>
#include <hip/hip_bf16.h>
#include <math.h>

using u16 = unsigned short;
using u32 = unsigned int;

typedef __attribute__((ext_vector_type(8))) short s8v;    // 8 x bf16 bits (4 VGPRs)
typedef __attribute__((ext_vector_type(4))) float f4v;    // MFMA acc

__device__ __forceinline__ float bf2f(u16 u) {
    u32 x = ((u32)u) << 16;
    return __builtin_bit_cast(float, x);
}
__device__ __forceinline__ u16 f2bf(float f) {
    u32 x = __builtin_bit_cast(u32, f);
    x += 0x7fffu + ((x >> 16) & 1u);
    return (u16)(x >> 16);
}

__device__ __forceinline__ f4v mfma_bf16(s8v a, s8v b, f4v c) {
    return __builtin_amdgcn_mfma_f32_16x16x32_bf16(a, b, c, 0, 0, 0);
}

#define GLL(srcp, dstp) __builtin_amdgcn_global_load_lds( \
    (const __attribute__((address_space(1))) void*)(srcp), \
    (__attribute__((address_space(3))) void*)(dstp), 16, 0, 0)

// Bijective XCD swizzle (m204): contiguous j-chunks per XCD, x-fastest within.
__device__ __forceinline__ void xcd_swz(int& bx, int& by, int& bz) {
    const int nx = gridDim.x, ny = gridDim.y;
    const int total = nx * ny * gridDim.z;
    int i = (bz * ny + by) * nx + bx;
    const int q = total >> 3, r = total & 7;
    const int xcd = i & 7, k = i >> 3;
    int j = ((xcd < r) ? xcd * (q + 1) : r * (q + 1) + (xcd - r) * q) + k;
    bx = j % nx; j /= nx;
    by = j % ny;
    bz = j / ny;
}

// BK=32 row-chunk swizzle: keeps 16-row column-slice ds_read_b128 at 2-way.
__device__ __forceinline__ int swzr32(int row) {
    return (row & 3) ^ ((row >> 2) & 1);
}

// ------------------------------------------------------------- tgemm3 ----
// m97-structure att-GEMM: C[M,N] = A[M,K] @ B[K,N], A bf16 [M,K], Bt[N,K].
// BM=BN=128, BK=32, SINGLE-buffered (32 KB LDS -> 4-5 blocks/CU; cross-block
// wave overlap supplies pipelining). 4 waves 2x2; wave tile 64x64; acc 4x4.
// M%128==0, K%32==0; N arbitrary (clamped stage, masked epilogue).
template<bool DO_ELU, bool OUT_F32, bool OUT_SPLIT>
__global__ __launch_bounds__(256) void tgemm3(
    const u16* __restrict__ A, const u16* __restrict__ Bt,
    void* __restrict__ Cv, int M, int N, int K,
    u16* __restrict__ Sh, u16* __restrict__ Sl, int Cp)
{
    constexpr int BM = 128, BN = 128, BK = 32;
    __shared__ __align__(16) u16 As[BM * BK];   // 8 KB
    __shared__ __align__(16) u16 Bs[BN * BK];   // 8 KB

    int bx = blockIdx.x, by = blockIdx.y, bz = blockIdx.z;
    xcd_swz(bx, by, bz);
    const int bm0 = by * BM, bn0 = bx * BN;
    const int tid = threadIdx.x;
    const int lane = tid & 63;
    const int wave = tid >> 6;
    const int wr = wave >> 1, wc = wave & 1;
    const int lr = lane & 15;
    const int srow = lane >> 2;      // 0..15: row within 16-row wave-chunk
    const int schk = lane & 3;       // 0..3: dest chunk

    f4v acc[4][4] = {};

    for (int k0 = 0; k0 < K; k0 += BK) {
#pragma unroll
        for (int ci = 0; ci < 2; ci++) {
            const int r16 = (wave * 2 + ci) * 16;
            const int row = r16 + srow;
            const int gchk = schk ^ swzr32(row);
            GLL(A + (size_t)(bm0 + row) * K + k0 + gchk * 8, &As[r16 * 32]);
        }
#pragma unroll
        for (int ci = 0; ci < 2; ci++) {
            const int r16 = (wave * 2 + ci) * 16;
            const int row = r16 + srow;
            int gn = bn0 + row;
            if (gn >= N) gn = N - 1;
            const int gchk = schk ^ swzr32(row);
            GLL(Bt + (size_t)gn * K + k0 + gchk * 8, &Bs[r16 * 32]);
        }
        __syncthreads();

        const int cbase = lane >> 4;     // k-group 0..3
        s8v a[4], b[4];
#pragma unroll
        for (int m = 0; m < 4; m++) {
            const int row = wr * 64 + m * 16 + lr;
            a[m] = *(const s8v*)&As[row * 32 + (cbase ^ swzr32(row)) * 8];
        }
#pragma unroll
        for (int n = 0; n < 4; n++) {
            const int row = wc * 64 + n * 16 + lr;
            b[n] = *(const s8v*)&Bs[row * 32 + (cbase ^ swzr32(row)) * 8];
        }
#pragma unroll
        for (int m = 0; m < 4; m++)
#pragma unroll
            for (int n = 0; n < 4; n++)
                acc[m][n] = mfma_bf16(a[m], b[n], acc[m][n]);
        __syncthreads();
    }

#pragma unroll
    for (int m = 0; m < 4; m++)
#pragma unroll
        for (int n = 0; n < 4; n++)
#pragma unroll
            for (int i = 0; i < 4; i++) {
                int gm = bm0 + wr * 64 + m * 16 + (lane >> 4) * 4 + i;
                int gn = bn0 + wc * 64 + n * 16 + lr;
                if (gm < M && gn < N) {
                    float val = acc[m][n][i];
                    if (DO_ELU) val = val > 0.f ? val : expm1f(val);
                    if (OUT_F32) {
                        ((float*)Cv)[(size_t)gm * N + gn] = val;
                        if (OUT_SPLIT) {
                            u16 hv = f2bf(val);
                            Sh[(size_t)gm * Cp + gn] = hv;
                            Sl[(size_t)gm * Cp + gn] = f2bf(val - bf2f(hv));
                        }
                    } else {
                        ((u16*)Cv)[(size_t)gm * N + gn] = f2bf(val);
                    }
                }
            }
}

// ------------------------------------------------------------- tgemm ----
// BN=64 att-GEMM (2-phase dbuf, BK=64) for mid-size grids (dec1).
template<bool DO_ELU, bool OUT_F32>
__global__ __launch_bounds__(256) void tgemm(
    const u16* __restrict__ A, const u16* __restrict__ Bt,
    void* __restrict__ Cv, int M, int N, int K)
{
    constexpr int BM = 128, BN = 64, BK = 64;
    __shared__ __align__(16) u16 As[2][BM * BK];
    __shared__ __align__(16) u16 Bs[2][BN * BK];

    int bx = blockIdx.x, by = blockIdx.y, bz = blockIdx.z;
    xcd_swz(bx, by, bz);
    const int bm0 = by * BM, bn0 = bx * BN;
    const int tid = threadIdx.x;
    const int lane = tid & 63;
    const int wave = tid >> 6;
    const int wr = wave >> 1, wc = wave & 1;
    const int lr = lane & 15;
    const int srow = lane >> 3, schk = lane & 7;

    f4v acc[4][2] = {};

    auto stage = [&](int buf, int k0) {
#pragma unroll
        for (int ci = 0; ci < 4; ci++) {
            const int r8 = (wave * 4 + ci) * 8;
            const int row = r8 + srow;
            const int gchk = schk ^ (row & 7);
            GLL(A + (size_t)(bm0 + row) * K + k0 + gchk * 8, &As[buf][r8 * 64]);
        }
#pragma unroll
        for (int ci = 0; ci < 2; ci++) {
            const int r8 = (wave * 2 + ci) * 8;
            const int row = r8 + srow;
            int gn = bn0 + row;
            if (gn >= N) gn = N - 1;
            const int gchk = schk ^ (row & 7);
            GLL(Bt + (size_t)gn * K + k0 + gchk * 8, &Bs[buf][r8 * 64]);
        }
    };

    stage(0, 0);
    __syncthreads();
    int cur = 0;
    for (int k0 = 0; k0 < K; k0 += BK) {
        if (k0 + BK < K) stage(cur ^ 1, k0 + BK);
#pragma unroll
        for (int kk = 0; kk < 2; kk++) {
            const int cbase = (lane >> 4) + kk * 4;
            s8v a[4], b[2];
#pragma unroll
            for (int m = 0; m < 4; m++) {
                const int row = wr * 64 + m * 16 + lr;
                a[m] = *(const s8v*)&As[cur][row * 64 + (cbase ^ (row & 7)) * 8];
            }
#pragma unroll
            for (int n = 0; n < 2; n++) {
                const int row = wc * 32 + n * 16 + lr;
                b[n] = *(const s8v*)&Bs[cur][row * 64 + (cbase ^ (row & 7)) * 8];
            }
#pragma unroll
            for (int m = 0; m < 4; m++)
#pragma unroll
                for (int n = 0; n < 2; n++)
                    acc[m][n] = mfma_bf16(a[m], b[n], acc[m][n]);
        }
        __syncthreads();
        cur ^= 1;
    }

#pragma unroll
    for (int m = 0; m < 4; m++)
#pragma unroll
        for (int n = 0; n < 2; n++)
#pragma unroll
            for (int i = 0; i < 4; i++) {
                int gm = bm0 + wr * 64 + m * 16 + (lane >> 4) * 4 + i;
                int gn = bn0 + wc * 32 + n * 16 + lr;
                if (gm < M && gn < N) {
                    float val = acc[m][n][i];
                    if (DO_ELU) val = val > 0.f ? val : expm1f(val);
                    if (OUT_F32) ((float*)Cv)[(size_t)gm * N + gn] = val;
                    else         ((u16*)Cv)[(size_t)gm * N + gn] = f2bf(val);
                }
            }
}

// ---------------------------------------------------------- tgemm_skd ----
// Dual-B stacked split-K att-GEMM (N=64): rows < Mh use BtA, else BtB.
__global__ __launch_bounds__(256) void tgemm_skd(
    const u16* __restrict__ A, const u16* __restrict__ BtA,
    const u16* __restrict__ BtB, float* __restrict__ P,
    int M, int Mh, int N, int K, int KS)
{
    constexpr int BM = 128, BN = 64, BK = 64;
    __shared__ __align__(16) u16 As[2][BM * BK];
    __shared__ __align__(16) u16 Bs[2][BN * BK];

    int bx = blockIdx.x, by = blockIdx.y, kz = blockIdx.z;
    xcd_swz(bx, by, kz);
    const int bm0 = by * BM, bn0 = bx * BN;
    const u16* Bt = (bm0 < Mh) ? BtA : BtB;
    const int tid = threadIdx.x;
    const int lane = tid & 63;
    const int wave = tid >> 6;
    const int wr = wave >> 1, wc = wave & 1;
    const int lr = lane & 15;
    const int srow = lane >> 3, schk = lane & 7;

    f4v acc[4][2] = {};

    auto stage = [&](int buf, int k0) {
#pragma unroll
        for (int ci = 0; ci < 4; ci++) {
            const int r8 = (wave * 4 + ci) * 8;
            const int row = r8 + srow;
            const int gchk = schk ^ (row & 7);
            GLL(A + (size_t)(bm0 + row) * K + k0 + gchk * 8, &As[buf][r8 * 64]);
        }
#pragma unroll
        for (int ci = 0; ci < 2; ci++) {
            const int r8 = (wave * 2 + ci) * 8;
            const int row = r8 + srow;
            int gn = bn0 + row;
            if (gn >= N) gn = N - 1;
            const int gchk = schk ^ (row & 7);
            GLL(Bt + (size_t)gn * K + k0 + gchk * 8, &Bs[buf][r8 * 64]);
        }
    };

    const int kbeg = kz * KS, kend = kbeg + KS;
    stage(0, kbeg);
    __syncthreads();
    int cur = 0;
    for (int k0 = kbeg; k0 < kend; k0 += BK) {
        if (k0 + BK < kend) stage(cur ^ 1, k0 + BK);
#pragma unroll
        for (int kk = 0; kk < 2; kk++) {
            const int cbase = (lane >> 4) + kk * 4;
            s8v a[4], b[2];
#pragma unroll
            for (int m = 0; m < 4; m++) {
                const int row = wr * 64 + m * 16 + lr;
                a[m] = *(const s8v*)&As[cur][row * 64 + (cbase ^ (row & 7)) * 8];
            }
#pragma unroll
            for (int n = 0; n < 2; n++) {
                const int row = wc * 32 + n * 16 + lr;
                b[n] = *(const s8v*)&Bs[cur][row * 64 + (cbase ^ (row & 7)) * 8];
            }
#pragma unroll
            for (int m = 0; m < 4; m++)
#pragma unroll
                for (int n = 0; n < 2; n++)
                    acc[m][n] = mfma_bf16(a[m], b[n], acc[m][n]);
        }
        __syncthreads();
        cur ^= 1;
    }

    float* Pz = P + (size_t)kz * M * N;
#pragma unroll
    for (int m = 0; m < 4; m++)
#pragma unroll
        for (int n = 0; n < 2; n++)
#pragma unroll
            for (int i = 0; i < 4; i++) {
                int gm = bm0 + wr * 64 + m * 16 + (lane >> 4) * 4 + i;
                int gn = bn0 + wc * 32 + n * 16 + lr;
                if (gm < M && gn < N)
                    Pz[(size_t)gm * N + gn] = acc[m][n][i];
            }
}

template<bool ELU>
__global__ __launch_bounds__(256) void skred_kernel(
    const float* __restrict__ P, u16* __restrict__ out, int total, int sk)
{
    int i = blockIdx.x * 256 + threadIdx.x;
    if (i >= total) return;
    float s = 0.f;
    for (int z = 0; z < sk; z++) s += P[(size_t)z * total + i];
    if (ELU) s = s > 0.f ? s : expm1f(s);
    out[i] = f2bf(s);
}

// ------------------------------------------------------------- tgemm2 ----
// Weight-GEMM (pre-split bf16 hi/lo), BK=32, 2-phase double-buffer.
template<bool ASP, bool SK>
__global__ __launch_bounds__(256) void tgemm2(
    const u16* __restrict__ A0, const u16* __restrict__ A1,
    const u16* __restrict__ Bt0, const u16* __restrict__ Bt1,
    void* __restrict__ Cv, int M, int N, int K, int KS)
{
    constexpr int BM = 128, BN = 64, BK = 32;
    __shared__ __align__(16) u16 As0[2][BM * BK];
    __shared__ __align__(16) u16 As1[ASP ? 2 : 1][ASP ? BM * BK : 8];
    __shared__ __align__(16) u16 Bs0[2][BN * BK];
    __shared__ __align__(16) u16 Bs1[2][BN * BK];

    int bx = blockIdx.x, by = blockIdx.y, kz = blockIdx.z;
    xcd_swz(bx, by, kz);
    const int bm0 = by * BM, bn0 = bx * BN;
    const int tid = threadIdx.x;
    const int lane = tid & 63;
    const int wave = tid >> 6;
    const int wr = wave >> 1, wc = wave & 1;
    const int lr = lane & 15;
    const int srow = lane >> 2;
    const int schk = lane & 3;

    f4v acc[4][2] = {};

    auto stage = [&](int buf, int k0) {
#pragma unroll
        for (int ci = 0; ci < 2; ci++) {
            const int r16 = (wave * 2 + ci) * 16;
            const int row = r16 + srow;
            const int gchk = schk ^ swzr32(row);
            const size_t goff = (size_t)(bm0 + row) * K + k0 + gchk * 8;
            GLL(A0 + goff, &As0[buf][r16 * 32]);
            if constexpr (ASP) GLL(A1 + goff, &As1[buf][r16 * 32]);
        }
        {
            const int r16 = wave * 16;
            const int row = r16 + srow;
            int gn = bn0 + row;
            if (gn >= N) gn = N - 1;
            const int gchk = schk ^ swzr32(row);
            const size_t goff = (size_t)gn * K + k0 + gchk * 8;
            GLL(Bt0 + goff, &Bs0[buf][r16 * 32]);
            GLL(Bt1 + goff, &Bs1[buf][r16 * 32]);
        }
    };

    const int kbeg = SK ? kz * KS : 0;
    const int kend = SK ? kbeg + KS : K;
    stage(0, kbeg);
    __syncthreads();
    int cur = 0;
    for (int k0 = kbeg; k0 < kend; k0 += BK) {
        if (k0 + BK < kend) stage(cur ^ 1, k0 + BK);
        {
            const int cbase = lane >> 4;
            s8v a0[4], a1[ASP ? 4 : 1], b0[2], b1[2];
#pragma unroll
            for (int m = 0; m < 4; m++) {
                const int row = wr * 64 + m * 16 + lr;
                const int o = row * 32 + (cbase ^ swzr32(row)) * 8;
                a0[m] = *(const s8v*)&As0[cur][o];
                if constexpr (ASP) a1[m] = *(const s8v*)&As1[cur][o];
            }
#pragma unroll
            for (int n = 0; n < 2; n++) {
                const int row = wc * 32 + n * 16 + lr;
                const int o = row * 32 + (cbase ^ swzr32(row)) * 8;
                b0[n] = *(const s8v*)&Bs0[cur][o];
                b1[n] = *(const s8v*)&Bs1[cur][o];
            }
#pragma unroll
            for (int m = 0; m < 4; m++)
#pragma unroll
                for (int n = 0; n < 2; n++) {
                    acc[m][n] = mfma_bf16(a0[m], b0[n], acc[m][n]);
                    acc[m][n] = mfma_bf16(a0[m], b1[n], acc[m][n]);
                    if constexpr (ASP) acc[m][n] = mfma_bf16(a1[m], b0[n], acc[m][n]);
                }
        }
        __syncthreads();
        cur ^= 1;
    }

#pragma unroll
    for (int m = 0; m < 4; m++)
#pragma unroll
        for (int n = 0; n < 2; n++)
#pragma unroll
            for (int i = 0; i < 4; i++) {
                int gm = bm0 + wr * 64 + m * 16 + (lane >> 4) * 4 + i;
                int gn = bn0 + wc * 32 + n * 16 + lr;
                if (gm < M && gn < N) {
                    if (SK) ((float*)Cv)[(size_t)kz * M * N + (size_t)gm * N + gn] = acc[m][n][i];
                    else    ((u16*)Cv)[(size_t)gm * N + gn] = f2bf(acc[m][n][i]);
                }
            }
}

// ------------------------------------------------------------- skredTS ----
__global__ __launch_bounds__(256) void skredTS_kernel(
    const float* __restrict__ P, const float* __restrict__ a,
    u16* __restrict__ wh, u16* __restrict__ tA, u16* __restrict__ tB,
    float* __restrict__ s1, float* __restrict__ s2, int n, int sk)
{
    __shared__ u16 lds[64][72];
    const int rowbase = blockIdx.x * 64;
    const int t = threadIdx.x;
    const int rl = t >> 2, cg = t & 3;
    const int row = rowbase + rl;
    const size_t M2 = (size_t)2 * n;

    float v[16];
#pragma unroll
    for (int k = 0; k < 16; k++) v[k] = 0.f;
    for (int z = 0; z < sk; z++) {
        const float4* p = (const float4*)&P[((size_t)z * M2 + row) * 64 + cg * 16];
#pragma unroll
        for (int q = 0; q < 4; q++) {
            float4 x = p[q];
            v[q * 4 + 0] += x.x; v[q * 4 + 1] += x.y;
            v[q * 4 + 2] += x.z; v[q * 4 + 3] += x.w;
        }
    }
    u16 w[16];
    float p1 = 0.f, p2 = 0.f;
#pragma unroll
    for (int k = 0; k < 16; k++) {
        w[k] = f2bf(v[k]);
        float vr = bf2f(w[k]);
        int f = cg * 16 + k;
        p1 += vr * a[f];
        p2 += vr * a[64 + f];
    }
    *(s8v*)&wh[(size_t)row * 64 + cg * 16]     = *(s8v*)&w[0];
    *(s8v*)&wh[(size_t)row * 64 + cg * 16 + 8] = *(s8v*)&w[8];
    *(s8v*)&lds[rl][cg * 16]     = *(s8v*)&w[0];
    *(s8v*)&lds[rl][cg * 16 + 8] = *(s8v*)&w[8];

    p1 += __shfl_down(p1, 1); p1 += __shfl_down(p1, 2);
    p2 += __shfl_down(p2, 1); p2 += __shfl_down(p2, 2);
    if (cg == 0) { s1[row] = p1; s2[row] = p2; }
    __syncthreads();

    const bool hb = rowbase >= n;
    u16* tX = hb ? tB : tA;
    const int grow = rowbase - (hb ? n : 0);
    u16 o[16];
#pragma unroll
    for (int k = 0; k < 16; k++) o[k] = lds[cg * 16 + k][rl];
    *(s8v*)&tX[(size_t)rl * n + grow + cg * 16]     = *(s8v*)&o[0];
    *(s8v*)&tX[(size_t)rl * n + grow + cg * 16 + 8] = *(s8v*)&o[8];
}

// -------------------------------------------------------------- splits ----
__global__ __launch_bounds__(256) void splitA_kernel(
    const float* __restrict__ src, u16* __restrict__ hi, u16* __restrict__ lo,
    int C, int Cp)
{
    int r = blockIdx.y;
    int c = blockIdx.x * 256 + threadIdx.x;
    if (c >= Cp) return;
    float v = (c < C) ? src[(size_t)r * C + c] : 0.f;
    u16 h = f2bf(v);
    hi[(size_t)r * Cp + c] = h;
    lo[(size_t)r * Cp + c] = f2bf(v - bf2f(h));
}

__global__ __launch_bounds__(256) void splitBT_kernel(
    const float* __restrict__ src, u16* __restrict__ hi, u16* __restrict__ lo,
    int R, int C, int Rp)
{
    __shared__ float t[32][33];
    const int r0 = blockIdx.y * 32, c0 = blockIdx.x * 32;
    const int tr = threadIdx.x >> 5, tc = threadIdx.x & 31;
#pragma unroll
    for (int i = 0; i < 4; i++) {
        int r = r0 + tr + i * 8, c = c0 + tc;
        t[tr + i * 8][tc] = (r < R && c < C) ? src[(size_t)r * C + c] : 0.f;
    }
    __syncthreads();
#pragma unroll
    for (int i = 0; i < 4; i++) {
        int c = c0 + tr + i * 8, r = r0 + tc;
        if (c < C && r < Rp) {
            float v = t[tc][tr + i * 8];
            u16 h = f2bf(v);
            hi[(size_t)c * Rp + r] = h;
            lo[(size_t)c * Rp + r] = f2bf(v - bf2f(h));
        }
    }
}

// ---------------------------------------------------------- transpose ----
__global__ __launch_bounds__(256) void tr_kernel(
    const u16* __restrict__ src, u16* __restrict__ dst, int R, int C)
{
    __shared__ u16 t[32][33];
    const int r0 = blockIdx.y * 32, c0 = blockIdx.x * 32;
    const int tr = threadIdx.x >> 5, tc = threadIdx.x & 31;
#pragma unroll
    for (int i = 0; i < 4; i++) {
        int r = r0 + tr + i * 8, c = c0 + tc;
        t[tr + i * 8][tc] = (r < R && c < C) ? src[(size_t)r * C + c] : (u16)0;
    }
    __syncthreads();
#pragma unroll
    for (int i = 0; i < 4; i++) {
        int c = c0 + tr + i * 8, r = r0 + tc;
        if (c < C && r < R) dst[(size_t)c * R + r] = t[tc][tr + i * 8];
    }
}

// ------------------------------------------------------------- reduce ----
__device__ __forceinline__ float block_sum4(float v, float* red) {
#pragma unroll
    for (int off = 32; off; off >>= 1) v += __shfl_down(v, off);
    int w = threadIdx.x >> 6;
    if ((threadIdx.x & 63) == 0) red[w] = v;
    __syncthreads();
    float r = red[0] + red[1] + red[2] + red[3];
    __syncthreads();
    return r;
}
__device__ __forceinline__ float block_max4(float v, float* red) {
#pragma unroll
    for (int off = 32; off; off >>= 1) v = fmaxf(v, __shfl_down(v, off));
    int w = threadIdx.x >> 6;
    if ((threadIdx.x & 63) == 0) red[w] = v;
    __syncthreads();
    float r = fmaxf(fmaxf(red[0], red[1]), fmaxf(red[2], red[3]));
    __syncthreads();
    return r;
}

// ------------------------------------------------------------- scores ----
__global__ __launch_bounds__(256) void scores_kernel(
    const u16* __restrict__ Wh, int ld, int F, const float* __restrict__ a,
    float* __restrict__ s1, float* __restrict__ s2)
{
    __shared__ float red[4];
    int i = blockIdx.x, tid = threadIdx.x;
    float acc1 = 0.f, acc2 = 0.f;
    for (int f = tid; f < F; f += 256) {
        float w = bf2f(Wh[(size_t)i * ld + f]);
        acc1 += w * a[f];
        acc2 += w * a[F + f];
    }
    acc1 = block_sum4(acc1, red);
    acc2 = block_sum4(acc2, red);
    if (tid == 0) { s1[i] = acc1; s2[i] = acc2; }
}

// ---------------------------------------------------------------- att ----
__device__ __forceinline__ void att_row(
    const u32* mask, const float* s1, const float* s2, int soff,
    u16* att, int i, int n, float* red)
{
    int tid = threadIdx.x;
    float s1i = s1[soff + i];
    int j0 = tid * 16;
    u32 w = mask[(size_t)i * (n >> 5) + (j0 >> 5)];
    u32 bits = (j0 & 16) ? (w >> 16) : (w & 0xFFFFu);

    float e[16];
    float mx = -3.0e38f;
#pragma unroll
    for (int t = 0; t < 16; t++) {
        float x = s1i + s2[soff + j0 + t];
        x = x > 0.f ? x : 0.2f * x;
        e[t] = x;
        if ((bits >> t) & 1u) mx = fmaxf(mx, x);
    }
    mx = block_max4(mx, red);

    float sum = 0.f;
#pragma unroll
    for (int t = 0; t < 16; t++) {
        float pv = ((bits >> t) & 1u) ? expf(e[t] - mx) : 0.f;
        e[t] = pv;
        sum += pv;
    }
    sum = block_sum4(sum, red);
    float rinv = sum > 0.f ? 1.f / sum : 0.f;
#pragma unroll
    for (int t = 0; t < 16; t++)
        att[(size_t)i * n + j0 + t] = f2bf(e[t] * rinv);
}

__global__ __launch_bounds__(256) void att_kernel(
    const u32* __restrict__ mask, const float* __restrict__ s1,
    const float* __restrict__ s2, u16* __restrict__ att, int n)
{
    __shared__ float red[4];
    att_row(mask, s1, s2, 0, att, blockIdx.x, n, red);
}

__global__ __launch_bounds__(256) void att2_kernel(
    const u32* __restrict__ maskA, const u32* __restrict__ maskB,
    const float* __restrict__ s1, const float* __restrict__ s2, int offB,
    u16* __restrict__ attA, u16* __restrict__ attB, int n)
{
    __shared__ float red[4];
    int b = blockIdx.x;
    if (b < n) att_row(maskA, s1, s2, 0, attA, b, n, red);
    else      att_row(maskB, s1, s2, offB, attB, b - n, n, red);
}

// --------------------------------------------------------------- fuse ----
__global__ __launch_bounds__(64) void fuse_kernel(
    const u16* __restrict__ E1, const u16* __restrict__ E2,
    const float* __restrict__ W, const float* __restrict__ U,
    float* __restrict__ fused, float* __restrict__ alpha,
    u16* __restrict__ eh, u16* __restrict__ el)
{
    __shared__ float e1[64], e2[64];
    int i = blockIdx.x, d = threadIdx.x;
    e1[d] = bf2f(E1[i * 64 + d]);
    e2[d] = bf2f(E2[i * 64 + d]);
    __syncthreads();
    float v1 = 0.f, v2 = 0.f;
#pragma unroll 8
    for (int f = 0; f < 64; f++) {
        float w = W[f * 64 + d];
        v1 += e1[f] * w;
        v2 += e2[f] * w;
    }
    v1 = tanhf(v1); v2 = tanhf(v2);
    float u = U[d];
    float p1 = v1 * u, p2 = v2 * u;
#pragma unroll
    for (int off = 32; off; off >>= 1) {
        p1 += __shfl_down(p1, off);
        p2 += __shfl_down(p2, off);
    }
    p1 = __shfl(p1, 0); p2 = __shfl(p2, 0);
    float m = fmaxf(p1, p2);
    float w1 = expf(p1 - m), w2 = expf(p2 - m);
    float a1 = w1 / (w1 + w2), a2 = w2 / (w1 + w2);
    float fv = a1 * e1[d] + a2 * e2[d];
    fused[i * 64 + d] = fv;
    if (eh != nullptr) {
        u16 hv = f2bf(fv);
        eh[i * 64 + d] = hv;
        el[i * 64 + d] = f2bf(fv - bf2f(hv));
    }
    if (alpha != nullptr && d < 2) alpha[i * 2 + d] = (d == 0 ? a1 : a2);
}

// ------------------------------------------------------------- bitpack ----
__global__ void bitpack_kernel(const int* __restrict__ adj,
                               u32* __restrict__ mask, int nwords)
{
    int w = blockIdx.x * 256 + threadIdx.x;
    if (w >= nwords) return;
    const int* src = adj + (size_t)w * 32;
    u32 m = 0;
#pragma unroll
    for (int b = 0; b < 32; b++) m |= (src[b] > 0 ? 1u : 0u) << b;
    mask[w] = m;
}

// ------------------------------------------------------------- driver ----
extern "C" void kernel_launch(void* const* d_in, const int* in_sizes, int n_in,
                              void* d_out, int out_size, void* d_ws, size_t ws_size,
                              hipStream_t stream)
{
    const int N = 4096, DIN = 3000, DINP = 3008, DH = 512, DO = 64;
    const float* x      = (const float*)d_in[0];
    const int*   adjF   = (const int*)d_in[1];
    const int*   adjS   = (const int*)d_in[2];
    const float* We1    = (const float*)d_in[3];
    const float* aE1    = (const float*)d_in[4];
    const float* We2    = (const float*)d_in[5];
    const float* aE2    = (const float*)d_in[6];
    const float* Wd1    = (const float*)d_in[7];
    const float* aD1    = (const float*)d_in[8];
    const float* Wd2    = (const float*)d_in[9];
    const float* aD2    = (const float*)d_in[10];
    const float* Womega = (const float*)d_in[11];
    const float* Uomega = (const float*)d_in[12];

    float* out       = (float*)d_out;
    float* out_emb   = out;                          // [4096,64]
    float* out_recon = out + (size_t)N * DO;         // [4096,3000]
    float* out_corr  = out_recon + (size_t)N * DIN;  // [4096,64]
    float* out_alpha = out_corr + (size_t)N * DO;    // [4096,2]

    char* ws = (char*)d_ws;
    size_t off = 0;
    auto alloc = [&](size_t bytes) {
        size_t o = off; off += (bytes + 255) & ~(size_t)255; return o;
    };
    const size_t o_att   = alloc((size_t)2 * N * N * 2);    // attF|attS, 67 MB
    const size_t o_maskF = alloc((size_t)N * (N / 32) * 4);
    const size_t o_maskS = alloc((size_t)N * (N / 32) * 4);
    const size_t o_s1    = alloc((size_t)2 * N * 4);        // stacked scores
    const size_t o_s2    = alloc((size_t)2 * N * 4);
    const size_t o_wh1   = alloc((size_t)N * DH * 2);       // wh1x / whc1
    const size_t o_h1    = alloc((size_t)2 * N * DH * 2);   // h1f|h1s (c1)
    const size_t o_whd1  = alloc((size_t)N * DH * 2);
    const size_t o_d1    = alloc((size_t)N * DH * 2);
    const size_t o_whd2  = alloc((size_t)N * DIN * 2);      // 24.6 MB
    const size_t o_wh2   = alloc((size_t)2 * N * DO * 2);   // stacked wh2/whc2
    const size_t o_h2    = alloc((size_t)2 * N * DO * 2);   // stacked h2/c2
    const size_t o_t512  = alloc((size_t)DH * N * 2);
    const size_t o_td1   = alloc((size_t)DH * N * 2);
    const size_t o_td2   = alloc((size_t)DIN * N * 2);      // 24.6 MB
    const size_t o_t64a  = alloc((size_t)DO * N * 2);
    const size_t o_t64b  = alloc((size_t)DO * N * 2);
    const size_t o_xh    = alloc((size_t)N * DINP * 2);     // 24.7 MB
    const size_t o_xl    = alloc((size_t)N * DINP * 2);
    const size_t o_we1th = alloc((size_t)DH * DINP * 2);
    const size_t o_we1tl = alloc((size_t)DH * DINP * 2);
    const size_t o_we2th = alloc((size_t)DO * DH * 2);
    const size_t o_we2tl = alloc((size_t)DO * DH * 2);
    const size_t o_wd1th = alloc((size_t)DH * DO * 2);
    const size_t o_wd1tl = alloc((size_t)DH * DO * 2);
    const size_t o_wd2th = alloc((size_t)DIN * DH * 2);
    const size_t o_wd2tl = alloc((size_t)DIN * DH * 2);
    const size_t o_eh    = alloc((size_t)N * DO * 2);
    const size_t o_el    = alloc((size_t)N * DO * 2);
    const size_t o_skp   = alloc((size_t)8 * 2 * N * DO * 4); // 16.8 MB

    u16* attF   = (u16*)(ws + o_att);
    u16* attS   = attF + (size_t)N * N;
    u32* maskF  = (u32*)(ws + o_maskF);
    u32* maskS  = (u32*)(ws + o_maskS);
    float* s1   = (float*)(ws + o_s1);
    float* s2   = (float*)(ws + o_s2);
    u16* wh1x   = (u16*)(ws + o_wh1);
    u16* whc1   = (u16*)(ws + o_wh1);
    u16* h1     = (u16*)(ws + o_h1);
    u16* whd1   = (u16*)(ws + o_whd1);
    u16* d1b    = (u16*)(ws + o_d1);
    u16* whd2   = (u16*)(ws + o_whd2);
    u16* wh2    = (u16*)(ws + o_wh2);
    u16* h2     = (u16*)(ws + o_h2);
    u16* h2f    = h2;
    u16* h2s    = h2 + (size_t)N * DO;
    u16* t512   = (u16*)(ws + o_t512);
    u16* td1    = (u16*)(ws + o_td1);
    u16* td2    = (u16*)(ws + o_td2);
    u16* t64a   = (u16*)(ws + o_t64a);
    u16* t64b   = (u16*)(ws + o_t64b);
    u16* xh     = (u16*)(ws + o_xh);
    u16* xl     = (u16*)(ws + o_xl);
    u16* we1th  = (u16*)(ws + o_we1th);
    u16* we1tl  = (u16*)(ws + o_we1tl);
    u16* we2th  = (u16*)(ws + o_we2th);
    u16* we2tl  = (u16*)(ws + o_we2tl);
    u16* wd1th  = (u16*)(ws + o_wd1th);
    u16* wd1tl  = (u16*)(ws + o_wd1tl);
    u16* wd2th  = (u16*)(ws + o_wd2th);
    u16* wd2tl  = (u16*)(ws + o_wd2tl);
    u16* eh     = (u16*)(ws + o_eh);
    u16* el     = (u16*)(ws + o_el);
    float* skp  = (float*)(ws + o_skp);

    auto grid64  = [](int M, int Nn) { return dim3((Nn + 63) / 64,  (M + 127) / 128); };
    auto grid128 = [](int M, int Nn) { return dim3((Nn + 127) / 128, (M + 127) / 128); };
    auto tr = [&](const u16* src, u16* dst, int R, int C) {
        tr_kernel<<<dim3((C + 31) / 32, (R + 31) / 32), 256, 0, stream>>>(src, dst, R, C);
    };
    auto scores = [&](const u16* Wh, int ld, int F, const float* a) {
        scores_kernel<<<N, 256, 0, stream>>>(Wh, ld, F, a, s1, s2);
    };
    // stacked layer-2 macro
    auto layer2 = [&](const u16* Astacked, u16* wh2buf, u16* h2out) {
        tgemm2<false, true><<<dim3(1, 64, 8), 256, 0, stream>>>(
            Astacked, nullptr, we2th, we2tl, skp, 2 * N, DO, DH, 64);
        skredTS_kernel<<<2 * N / 64, 256, 0, stream>>>(
            skp, aE2, wh2buf, t64a, t64b, s1, s2, N, 8);
        att2_kernel<<<2 * N, 256, 0, stream>>>(
            maskF, maskS, s1, s2, N, attF, attS, N);
        tgemm_skd<<<dim3(1, 64, 8), 256, 0, stream>>>(
            attF, t64a, t64b, skp, 2 * N, N, DO, N, 512);
        skred_kernel<true><<<(2 * N * DO + 255) / 256, 256, 0, stream>>>(
            skp, h2out, 2 * N * DO, 8);
    };

    // ---- prep ----
    bitpack_kernel<<<(N * (N / 32) + 255) / 256, 256, 0, stream>>>(adjF, maskF, N * (N / 32));
    bitpack_kernel<<<(N * (N / 32) + 255) / 256, 256, 0, stream>>>(adjS, maskS, N * (N / 32));
    splitA_kernel<<<dim3((DINP + 255) / 256, N), 256, 0, stream>>>(x, xh, xl, DIN, DINP);
    splitBT_kernel<<<dim3((DH + 31) / 32, (DINP + 31) / 32), 256, 0, stream>>>(We1, we1th, we1tl, DIN, DH, DINP);
    splitBT_kernel<<<dim3((DO + 31) / 32, (DH + 31) / 32), 256, 0, stream>>>(We2, we2th, we2tl, DH, DO, DH);
    splitBT_kernel<<<dim3((DH + 31) / 32, (DO + 31) / 32), 256, 0, stream>>>(Wd1, wd1th, wd1tl, DO, DH, DO);
    splitBT_kernel<<<dim3((DIN + 31) / 32, (DH + 31) / 32), 256, 0, stream>>>(Wd2, wd2th, wd2tl, DH, DIN, DH);

    // ---- encoder layer 1 ----
    tgemm2<true, false><<<grid64(N, DH), 256, 0, stream>>>(
        xh, xl, we1th, we1tl, wh1x, N, DH, DINP, DINP);
    tr(wh1x, t512, N, DH);
    scores(wh1x, DH, DH, aE1);
    att2_kernel<<<2 * N, 256, 0, stream>>>(maskF, maskS, s1, s2, 0, attF, attS, N);
    tgemm3<true, false, false><<<grid128(2 * N, DH), 256, 0, stream>>>(
        attF, t512, h1, 2 * N, DH, N, nullptr, nullptr, 0);   // h1f|h1s stacked

    // ---- encoder layer 2 (stacked) ----
    layer2(h1, wh2, h2);

    // ---- fuse -> emb_latent + alpha + eh/el split ----
    fuse_kernel<<<N, 64, 0, stream>>>(h2f, h2s, Womega, Uomega, out_emb, out_alpha, eh, el);

    // ---- decoder layer 1 (spatial adj) ----
    tgemm2<true, false><<<grid64(N, DH), 256, 0, stream>>>(
        eh, el, wd1th, wd1tl, whd1, N, DH, DO, DO);
    tr(whd1, td1, N, DH);
    scores(whd1, DH, DH, aD1);
    att_kernel<<<N, 256, 0, stream>>>(maskS, s1, s2, attS, N);
    tgemm<true, false><<<grid64(N, DH), 256, 0, stream>>>(
        attS, td1, d1b, N, DH, N);

    // ---- decoder layer 2 (spatial adj); recon f32 + hi/lo split ----
    tgemm2<false, false><<<grid64(N, DIN), 256, 0, stream>>>(
        d1b, nullptr, wd2th, wd2tl, whd2, N, DIN, DH, DH);
    tr(whd2, td2, N, DIN);
    scores(whd2, DIN, DIN, aD2);
    att_kernel<<<N, 256, 0, stream>>>(maskS, s1, s2, attS, N);
    tgemm3<true, true, true><<<grid128(N, DIN), 256, 0, stream>>>(
        attS, td2, out_recon, N, DIN, N, xh, xl, DINP);

    // ---- corr encoder layer 1 (A = recon split in xh/xl) ----
    tgemm2<true, false><<<grid64(N, DH), 256, 0, stream>>>(
        xh, xl, we1th, we1tl, whc1, N, DH, DINP, DINP);
    tr(whc1, t512, N, DH);
    scores(whc1, DH, DH, aE1);
    att2_kernel<<<2 * N, 256, 0, stream>>>(maskF, maskS, s1, s2, 0, attF, attS, N);
    tgemm3<true, false, false><<<grid128(2 * N, DH), 256, 0, stream>>>(
        attF, t512, h1, 2 * N, DH, N, nullptr, nullptr, 0);   // c1f|c1s stacked

    // ---- corr encoder layer 2 (stacked) ----
    layer2(h1, wh2, h2);

    // ---- fuse -> corr ----
    fuse_kernel<<<N, 64, 0, stream>>>(h2f, h2s, Womega, Uomega, out_corr, nullptr, nullptr, nullptr);
}

// Round 10
// 991.984 us; speedup vs baseline: 1.2501x; 1.2501x over previous
//
#include <hip/hip_runtime.h>
#include <hip/hip_bf16.h>
#include <math.h>

using u16 = unsigned short;
using u32 = unsigned int;

typedef __attribute__((ext_vector_type(8))) short s8v;    // 8 x bf16 bits (4 VGPRs)
typedef __attribute__((ext_vector_type(4))) float f4v;    // MFMA acc

__device__ __forceinline__ float bf2f(u16 u) {
    u32 x = ((u32)u) << 16;
    return __builtin_bit_cast(float, x);
}
__device__ __forceinline__ u16 f2bf(float f) {
    u32 x = __builtin_bit_cast(u32, f);
    x += 0x7fffu + ((x >> 16) & 1u);
    return (u16)(x >> 16);
}

__device__ __forceinline__ f4v mfma_bf16(s8v a, s8v b, f4v c) {
    return __builtin_amdgcn_mfma_f32_16x16x32_bf16(a, b, c, 0, 0, 0);
}

#define GLL(srcp, dstp) __builtin_amdgcn_global_load_lds( \
    (const __attribute__((address_space(1))) void*)(srcp), \
    (__attribute__((address_space(3))) void*)(dstp), 16, 0, 0)

// Bijective XCD swizzle (m204): contiguous j-chunks per XCD, x-fastest within.
__device__ __forceinline__ void xcd_swz(int& bx, int& by, int& bz) {
    const int nx = gridDim.x, ny = gridDim.y;
    const int total = nx * ny * gridDim.z;
    int i = (bz * ny + by) * nx + bx;
    const int q = total >> 3, r = total & 7;
    const int xcd = i & 7, k = i >> 3;
    int j = ((xcd < r) ? xcd * (q + 1) : r * (q + 1) + (xcd - r) * q) + k;
    bx = j % nx; j /= nx;
    by = j % ny;
    bz = j / ny;
}

// ------------------------------------------------------------- tgemm ----
// att-GEMM: C[M,N] = A[M,K] @ B[K,N], A bf16 [M,K], Bt[N,K] bf16.
// global_load_lds w=16, linear LDS + XOR chunk swizzle (chunk^=(row&7)),
// 2-phase double-buffer. M%128==0, K%64==0; N arbitrary.
// OUT_SPLIT (with OUT_F32): also writes bf16 hi/lo at stride Cp.
template<bool DO_ELU, bool OUT_F32, bool OUT_SPLIT>
__global__ __launch_bounds__(256) void tgemm(
    const u16* __restrict__ A, const u16* __restrict__ Bt,
    void* __restrict__ Cv, int M, int N, int K,
    u16* __restrict__ Sh, u16* __restrict__ Sl, int Cp)
{
    constexpr int BM = 128, BN = 64, BK = 64;
    __shared__ __align__(16) u16 As[2][BM * BK];
    __shared__ __align__(16) u16 Bs[2][BN * BK];

    int bx = blockIdx.x, by = blockIdx.y, bz = blockIdx.z;
    xcd_swz(bx, by, bz);
    const int bm0 = by * BM, bn0 = bx * BN;
    const int tid = threadIdx.x;
    const int lane = tid & 63;
    const int wave = tid >> 6;
    const int wr = wave >> 1, wc = wave & 1;
    const int lr = lane & 15;
    const int srow = lane >> 3, schk = lane & 7;

    f4v acc[4][2] = {};

    auto stage = [&](int buf, int k0) {
#pragma unroll
        for (int ci = 0; ci < 4; ci++) {
            const int r8 = (wave * 4 + ci) * 8;
            const int row = r8 + srow;
            const int gchk = schk ^ (row & 7);
            GLL(A + (size_t)(bm0 + row) * K + k0 + gchk * 8, &As[buf][r8 * 64]);
        }
#pragma unroll
        for (int ci = 0; ci < 2; ci++) {
            const int r8 = (wave * 2 + ci) * 8;
            const int row = r8 + srow;
            int gn = bn0 + row;
            if (gn >= N) gn = N - 1;
            const int gchk = schk ^ (row & 7);
            GLL(Bt + (size_t)gn * K + k0 + gchk * 8, &Bs[buf][r8 * 64]);
        }
    };

    stage(0, 0);
    __syncthreads();
    int cur = 0;
    for (int k0 = 0; k0 < K; k0 += BK) {
        if (k0 + BK < K) stage(cur ^ 1, k0 + BK);
#pragma unroll
        for (int kk = 0; kk < 2; kk++) {
            const int cbase = (lane >> 4) + kk * 4;
            s8v a[4], b[2];
#pragma unroll
            for (int m = 0; m < 4; m++) {
                const int row = wr * 64 + m * 16 + lr;
                a[m] = *(const s8v*)&As[cur][row * 64 + (cbase ^ (row & 7)) * 8];
            }
#pragma unroll
            for (int n = 0; n < 2; n++) {
                const int row = wc * 32 + n * 16 + lr;
                b[n] = *(const s8v*)&Bs[cur][row * 64 + (cbase ^ (row & 7)) * 8];
            }
#pragma unroll
            for (int m = 0; m < 4; m++)
#pragma unroll
                for (int n = 0; n < 2; n++)
                    acc[m][n] = mfma_bf16(a[m], b[n], acc[m][n]);
        }
        __syncthreads();
        cur ^= 1;
    }

#pragma unroll
    for (int m = 0; m < 4; m++)
#pragma unroll
        for (int n = 0; n < 2; n++)
#pragma unroll
            for (int i = 0; i < 4; i++) {
                int gm = bm0 + wr * 64 + m * 16 + (lane >> 4) * 4 + i;
                int gn = bn0 + wc * 32 + n * 16 + lr;
                if (gm < M && gn < N) {
                    float val = acc[m][n][i];
                    if (DO_ELU) val = val > 0.f ? val : expm1f(val);
                    if (OUT_F32) {
                        ((float*)Cv)[(size_t)gm * N + gn] = val;
                        if (OUT_SPLIT) {
                            u16 hv = f2bf(val);
                            Sh[(size_t)gm * Cp + gn] = hv;
                            Sl[(size_t)gm * Cp + gn] = f2bf(val - bf2f(hv));
                        }
                    } else {
                        ((u16*)Cv)[(size_t)gm * N + gn] = f2bf(val);
                    }
                }
            }
}

// ---------------------------------------------------------- tgemm_skd ----
// Dual-B stacked split-K att-GEMM (N=64): rows < Mh use BtA, else BtB.
// grid (1, M/128, z); f32 partials P[z][M][N].
__global__ __launch_bounds__(256) void tgemm_skd(
    const u16* __restrict__ A, const u16* __restrict__ BtA,
    const u16* __restrict__ BtB, float* __restrict__ P,
    int M, int Mh, int N, int K, int KS)
{
    constexpr int BM = 128, BN = 64, BK = 64;
    __shared__ __align__(16) u16 As[2][BM * BK];
    __shared__ __align__(16) u16 Bs[2][BN * BK];

    int bx = blockIdx.x, by = blockIdx.y, kz = blockIdx.z;
    xcd_swz(bx, by, kz);
    const int bm0 = by * BM, bn0 = bx * BN;
    const u16* Bt = (bm0 < Mh) ? BtA : BtB;
    const int tid = threadIdx.x;
    const int lane = tid & 63;
    const int wave = tid >> 6;
    const int wr = wave >> 1, wc = wave & 1;
    const int lr = lane & 15;
    const int srow = lane >> 3, schk = lane & 7;

    f4v acc[4][2] = {};

    auto stage = [&](int buf, int k0) {
#pragma unroll
        for (int ci = 0; ci < 4; ci++) {
            const int r8 = (wave * 4 + ci) * 8;
            const int row = r8 + srow;
            const int gchk = schk ^ (row & 7);
            GLL(A + (size_t)(bm0 + row) * K + k0 + gchk * 8, &As[buf][r8 * 64]);
        }
#pragma unroll
        for (int ci = 0; ci < 2; ci++) {
            const int r8 = (wave * 2 + ci) * 8;
            const int row = r8 + srow;
            int gn = bn0 + row;
            if (gn >= N) gn = N - 1;
            const int gchk = schk ^ (row & 7);
            GLL(Bt + (size_t)gn * K + k0 + gchk * 8, &Bs[buf][r8 * 64]);
        }
    };

    const int kbeg = kz * KS, kend = kbeg + KS;
    stage(0, kbeg);
    __syncthreads();
    int cur = 0;
    for (int k0 = kbeg; k0 < kend; k0 += BK) {
        if (k0 + BK < kend) stage(cur ^ 1, k0 + BK);
#pragma unroll
        for (int kk = 0; kk < 2; kk++) {
            const int cbase = (lane >> 4) + kk * 4;
            s8v a[4], b[2];
#pragma unroll
            for (int m = 0; m < 4; m++) {
                const int row = wr * 64 + m * 16 + lr;
                a[m] = *(const s8v*)&As[cur][row * 64 + (cbase ^ (row & 7)) * 8];
            }
#pragma unroll
            for (int n = 0; n < 2; n++) {
                const int row = wc * 32 + n * 16 + lr;
                b[n] = *(const s8v*)&Bs[cur][row * 64 + (cbase ^ (row & 7)) * 8];
            }
#pragma unroll
            for (int m = 0; m < 4; m++)
#pragma unroll
                for (int n = 0; n < 2; n++)
                    acc[m][n] = mfma_bf16(a[m], b[n], acc[m][n]);
        }
        __syncthreads();
        cur ^= 1;
    }

    float* Pz = P + (size_t)kz * M * N;
#pragma unroll
    for (int m = 0; m < 4; m++)
#pragma unroll
        for (int n = 0; n < 2; n++)
#pragma unroll
            for (int i = 0; i < 4; i++) {
                int gm = bm0 + wr * 64 + m * 16 + (lane >> 4) * 4 + i;
                int gn = bn0 + wc * 32 + n * 16 + lr;
                if (gm < M && gn < N)
                    Pz[(size_t)gm * N + gn] = acc[m][n][i];
            }
}

template<bool ELU>
__global__ __launch_bounds__(256) void skred_kernel(
    const float* __restrict__ P, u16* __restrict__ out, int total, int sk)
{
    int i = blockIdx.x * 256 + threadIdx.x;
    if (i >= total) return;
    float s = 0.f;
    for (int z = 0; z < sk; z++) s += P[(size_t)z * total + i];
    if (ELU) s = s > 0.f ? s : expm1f(s);
    out[i] = f2bf(s);
}

// ------------------------------------------------------------- tgemm2 ----
// Weight-GEMM (pre-split bf16 hi/lo), BK=32, 2-phase double-buffer.
// Chunk swizzle (row&3)^((row>>2)&1) keeps ds_read_b128 <=2-way.
// SK: grid.z slices K, f32 partials to Cv.
template<bool ASP, bool SK>
__global__ __launch_bounds__(256) void tgemm2(
    const u16* __restrict__ A0, const u16* __restrict__ A1,
    const u16* __restrict__ Bt0, const u16* __restrict__ Bt1,
    void* __restrict__ Cv, int M, int N, int K, int KS)
{
    constexpr int BM = 128, BN = 64, BK = 32;
    __shared__ __align__(16) u16 As0[2][BM * BK];
    __shared__ __align__(16) u16 As1[ASP ? 2 : 1][ASP ? BM * BK : 8];
    __shared__ __align__(16) u16 Bs0[2][BN * BK];
    __shared__ __align__(16) u16 Bs1[2][BN * BK];

    int bx = blockIdx.x, by = blockIdx.y, kz = blockIdx.z;
    xcd_swz(bx, by, kz);
    const int bm0 = by * BM, bn0 = bx * BN;
    const int tid = threadIdx.x;
    const int lane = tid & 63;
    const int wave = tid >> 6;
    const int wr = wave >> 1, wc = wave & 1;
    const int lr = lane & 15;
    const int srow = lane >> 2;      // 16 rows per 1KB wave-chunk
    const int schk = lane & 3;       // 4 chunks per 64B row

    auto swzr = [](int row) { return (row & 3) ^ ((row >> 2) & 1); };

    f4v acc[4][2] = {};

    auto stage = [&](int buf, int k0) {
#pragma unroll
        for (int ci = 0; ci < 2; ci++) {
            const int r16 = (wave * 2 + ci) * 16;
            const int row = r16 + srow;
            const int gchk = schk ^ swzr(row);
            const size_t goff = (size_t)(bm0 + row) * K + k0 + gchk * 8;
            GLL(A0 + goff, &As0[buf][r16 * 32]);
            if constexpr (ASP) GLL(A1 + goff, &As1[buf][r16 * 32]);
        }
        {
            const int r16 = wave * 16;
            const int row = r16 + srow;
            int gn = bn0 + row;
            if (gn >= N) gn = N - 1;
            const int gchk = schk ^ swzr(row);
            const size_t goff = (size_t)gn * K + k0 + gchk * 8;
            GLL(Bt0 + goff, &Bs0[buf][r16 * 32]);
            GLL(Bt1 + goff, &Bs1[buf][r16 * 32]);
        }
    };

    const int kbeg = SK ? kz * KS : 0;
    const int kend = SK ? kbeg + KS : K;
    stage(0, kbeg);
    __syncthreads();
    int cur = 0;
    for (int k0 = kbeg; k0 < kend; k0 += BK) {
        if (k0 + BK < kend) stage(cur ^ 1, k0 + BK);
        {
            const int cbase = lane >> 4;     // 0..3
            s8v a0[4], a1[ASP ? 4 : 1], b0[2], b1[2];
#pragma unroll
            for (int m = 0; m < 4; m++) {
                const int row = wr * 64 + m * 16 + lr;
                const int o = row * 32 + (cbase ^ swzr(row)) * 8;
                a0[m] = *(const s8v*)&As0[cur][o];
                if constexpr (ASP) a1[m] = *(const s8v*)&As1[cur][o];
            }
#pragma unroll
            for (int n = 0; n < 2; n++) {
                const int row = wc * 32 + n * 16 + lr;
                const int o = row * 32 + (cbase ^ swzr(row)) * 8;
                b0[n] = *(const s8v*)&Bs0[cur][o];
                b1[n] = *(const s8v*)&Bs1[cur][o];
            }
#pragma unroll
            for (int m = 0; m < 4; m++)
#pragma unroll
                for (int n = 0; n < 2; n++) {
                    acc[m][n] = mfma_bf16(a0[m], b0[n], acc[m][n]);
                    acc[m][n] = mfma_bf16(a0[m], b1[n], acc[m][n]);
                    if constexpr (ASP) acc[m][n] = mfma_bf16(a1[m], b0[n], acc[m][n]);
                }
        }
        __syncthreads();
        cur ^= 1;
    }

#pragma unroll
    for (int m = 0; m < 4; m++)
#pragma unroll
        for (int n = 0; n < 2; n++)
#pragma unroll
            for (int i = 0; i < 4; i++) {
                int gm = bm0 + wr * 64 + m * 16 + (lane >> 4) * 4 + i;
                int gn = bn0 + wc * 32 + n * 16 + lr;
                if (gm < M && gn < N) {
                    if (SK) ((float*)Cv)[(size_t)kz * M * N + (size_t)gm * N + gn] = acc[m][n][i];
                    else    ((u16*)Cv)[(size_t)gm * N + gn] = f2bf(acc[m][n][i]);
                }
            }
}

// ------------------------------------------------------------- skredTS ----
// Fused: split-K partial sum -> bf16 [2N][64] + transposed [64][N] halves
// + scores dot (s1,s2 stacked). 64 rows/block; thread = (row, 16-col group).
__global__ __launch_bounds__(256) void skredTS_kernel(
    const float* __restrict__ P, const float* __restrict__ a,
    u16* __restrict__ wh, u16* __restrict__ tA, u16* __restrict__ tB,
    float* __restrict__ s1, float* __restrict__ s2, int n, int sk)
{
    __shared__ u16 lds[64][72];
    const int rowbase = blockIdx.x * 64;
    const int t = threadIdx.x;
    const int rl = t >> 2, cg = t & 3;
    const int row = rowbase + rl;
    const size_t M2 = (size_t)2 * n;

    float v[16];
#pragma unroll
    for (int k = 0; k < 16; k++) v[k] = 0.f;
    for (int z = 0; z < sk; z++) {
        const float4* p = (const float4*)&P[((size_t)z * M2 + row) * 64 + cg * 16];
#pragma unroll
        for (int q = 0; q < 4; q++) {
            float4 x = p[q];
            v[q * 4 + 0] += x.x; v[q * 4 + 1] += x.y;
            v[q * 4 + 2] += x.z; v[q * 4 + 3] += x.w;
        }
    }
    u16 w[16];
    float p1 = 0.f, p2 = 0.f;
#pragma unroll
    for (int k = 0; k < 16; k++) {
        w[k] = f2bf(v[k]);
        float vr = bf2f(w[k]);
        int f = cg * 16 + k;
        p1 += vr * a[f];
        p2 += vr * a[64 + f];
    }
    *(s8v*)&wh[(size_t)row * 64 + cg * 16]     = *(s8v*)&w[0];
    *(s8v*)&wh[(size_t)row * 64 + cg * 16 + 8] = *(s8v*)&w[8];
    *(s8v*)&lds[rl][cg * 16]     = *(s8v*)&w[0];
    *(s8v*)&lds[rl][cg * 16 + 8] = *(s8v*)&w[8];

    p1 += __shfl_down(p1, 1); p1 += __shfl_down(p1, 2);
    p2 += __shfl_down(p2, 1); p2 += __shfl_down(p2, 2);
    if (cg == 0) { s1[row] = p1; s2[row] = p2; }
    __syncthreads();

    // transpose out: thread -> col rl, rows cg*16..+16
    const bool hb = rowbase >= n;
    u16* tX = hb ? tB : tA;
    const int grow = rowbase - (hb ? n : 0);
    u16 o[16];
#pragma unroll
    for (int k = 0; k < 16; k++) o[k] = lds[cg * 16 + k][rl];
    *(s8v*)&tX[(size_t)rl * n + grow + cg * 16]     = *(s8v*)&o[0];
    *(s8v*)&tX[(size_t)rl * n + grow + cg * 16 + 8] = *(s8v*)&o[8];
}

// -------------------------------------------------------------- splits ----
__global__ __launch_bounds__(256) void splitA_kernel(
    const float* __restrict__ src, u16* __restrict__ hi, u16* __restrict__ lo,
    int C, int Cp)
{
    int r = blockIdx.y;
    int c = blockIdx.x * 256 + threadIdx.x;
    if (c >= Cp) return;
    float v = (c < C) ? src[(size_t)r * C + c] : 0.f;
    u16 h = f2bf(v);
    hi[(size_t)r * Cp + c] = h;
    lo[(size_t)r * Cp + c] = f2bf(v - bf2f(h));
}

__global__ __launch_bounds__(256) void splitBT_kernel(
    const float* __restrict__ src, u16* __restrict__ hi, u16* __restrict__ lo,
    int R, int C, int Rp)
{
    __shared__ float t[32][33];
    const int r0 = blockIdx.y * 32, c0 = blockIdx.x * 32;
    const int tr = threadIdx.x >> 5, tc = threadIdx.x & 31;
#pragma unroll
    for (int i = 0; i < 4; i++) {
        int r = r0 + tr + i * 8, c = c0 + tc;
        t[tr + i * 8][tc] = (r < R && c < C) ? src[(size_t)r * C + c] : 0.f;
    }
    __syncthreads();
#pragma unroll
    for (int i = 0; i < 4; i++) {
        int c = c0 + tr + i * 8, r = r0 + tc;
        if (c < C && r < Rp) {
            float v = t[tc][tr + i * 8];
            u16 h = f2bf(v);
            hi[(size_t)c * Rp + r] = h;
            lo[(size_t)c * Rp + r] = f2bf(v - bf2f(h));
        }
    }
}

// ---------------------------------------------------------- transpose ----
__global__ __launch_bounds__(256) void tr_kernel(
    const u16* __restrict__ src, u16* __restrict__ dst, int R, int C)
{
    __shared__ u16 t[32][33];
    const int r0 = blockIdx.y * 32, c0 = blockIdx.x * 32;
    const int tr = threadIdx.x >> 5, tc = threadIdx.x & 31;
#pragma unroll
    for (int i = 0; i < 4; i++) {
        int r = r0 + tr + i * 8, c = c0 + tc;
        t[tr + i * 8][tc] = (r < R && c < C) ? src[(size_t)r * C + c] : (u16)0;
    }
    __syncthreads();
#pragma unroll
    for (int i = 0; i < 4; i++) {
        int c = c0 + tr + i * 8, r = r0 + tc;
        if (c < C && r < R) dst[(size_t)c * R + r] = t[tc][tr + i * 8];
    }
}

// ------------------------------------------------------------- reduce ----
__device__ __forceinline__ float block_sum4(float v, float* red) {
#pragma unroll
    for (int off = 32; off; off >>= 1) v += __shfl_down(v, off);
    int w = threadIdx.x >> 6;
    if ((threadIdx.x & 63) == 0) red[w] = v;
    __syncthreads();
    float r = red[0] + red[1] + red[2] + red[3];
    __syncthreads();
    return r;
}
__device__ __forceinline__ float block_max4(float v, float* red) {
#pragma unroll
    for (int off = 32; off; off >>= 1) v = fmaxf(v, __shfl_down(v, off));
    int w = threadIdx.x >> 6;
    if ((threadIdx.x & 63) == 0) red[w] = v;
    __syncthreads();
    float r = fmaxf(fmaxf(red[0], red[1]), fmaxf(red[2], red[3]));
    __syncthreads();
    return r;
}

// ------------------------------------------------------------- scores ----
__global__ __launch_bounds__(256) void scores_kernel(
    const u16* __restrict__ Wh, int ld, int F, const float* __restrict__ a,
    float* __restrict__ s1, float* __restrict__ s2)
{
    __shared__ float red[4];
    int i = blockIdx.x, tid = threadIdx.x;
    float acc1 = 0.f, acc2 = 0.f;
    for (int f = tid; f < F; f += 256) {
        float w = bf2f(Wh[(size_t)i * ld + f]);
        acc1 += w * a[f];
        acc2 += w * a[F + f];
    }
    acc1 = block_sum4(acc1, red);
    acc2 = block_sum4(acc2, red);
    if (tid == 0) { s1[i] = acc1; s2[i] = acc2; }
}

// ---------------------------------------------------------------- att ----
__device__ __forceinline__ void att_row(
    const u32* mask, const float* s1, const float* s2, int soff,
    u16* att, int i, int n, float* red)
{
    int tid = threadIdx.x;
    float s1i = s1[soff + i];
    int j0 = tid * 16;
    u32 w = mask[(size_t)i * (n >> 5) + (j0 >> 5)];
    u32 bits = (j0 & 16) ? (w >> 16) : (w & 0xFFFFu);

    float e[16];
    float mx = -3.0e38f;
#pragma unroll
    for (int t = 0; t < 16; t++) {
        float x = s1i + s2[soff + j0 + t];
        x = x > 0.f ? x : 0.2f * x;
        e[t] = x;
        if ((bits >> t) & 1u) mx = fmaxf(mx, x);
    }
    mx = block_max4(mx, red);

    float sum = 0.f;
#pragma unroll
    for (int t = 0; t < 16; t++) {
        float pv = ((bits >> t) & 1u) ? expf(e[t] - mx) : 0.f;
        e[t] = pv;
        sum += pv;
    }
    sum = block_sum4(sum, red);
    float rinv = sum > 0.f ? 1.f / sum : 0.f;
#pragma unroll
    for (int t = 0; t < 16; t++)
        att[(size_t)i * n + j0 + t] = f2bf(e[t] * rinv);
}

__global__ __launch_bounds__(256) void att_kernel(
    const u32* __restrict__ mask, const float* __restrict__ s1,
    const float* __restrict__ s2, u16* __restrict__ att, int n)
{
    __shared__ float red[4];
    att_row(mask, s1, s2, 0, att, blockIdx.x, n, red);
}

// dual: blocks [0,n) -> maskA/attA (soff 0); [n,2n) -> maskB/attB (soff offB)
__global__ __launch_bounds__(256) void att2_kernel(
    const u32* __restrict__ maskA, const u32* __restrict__ maskB,
    const float* __restrict__ s1, const float* __restrict__ s2, int offB,
    u16* __restrict__ attA, u16* __restrict__ attB, int n)
{
    __shared__ float red[4];
    int b = blockIdx.x;
    if (b < n) att_row(maskA, s1, s2, 0, attA, b, n, red);
    else      att_row(maskB, s1, s2, offB, attB, b - n, n, red);
}

// --------------------------------------------------------------- fuse ----
__global__ __launch_bounds__(64) void fuse_kernel(
    const u16* __restrict__ E1, const u16* __restrict__ E2,
    const float* __restrict__ W, const float* __restrict__ U,
    float* __restrict__ fused, float* __restrict__ alpha,
    u16* __restrict__ eh, u16* __restrict__ el)
{
    __shared__ float e1[64], e2[64];
    int i = blockIdx.x, d = threadIdx.x;
    e1[d] = bf2f(E1[i * 64 + d]);
    e2[d] = bf2f(E2[i * 64 + d]);
    __syncthreads();
    float v1 = 0.f, v2 = 0.f;
#pragma unroll 8
    for (int f = 0; f < 64; f++) {
        float w = W[f * 64 + d];
        v1 += e1[f] * w;
        v2 += e2[f] * w;
    }
    v1 = tanhf(v1); v2 = tanhf(v2);
    float u = U[d];
    float p1 = v1 * u, p2 = v2 * u;
#pragma unroll
    for (int off = 32; off; off >>= 1) {
        p1 += __shfl_down(p1, off);
        p2 += __shfl_down(p2, off);
    }
    p1 = __shfl(p1, 0); p2 = __shfl(p2, 0);
    float m = fmaxf(p1, p2);
    float w1 = expf(p1 - m), w2 = expf(p2 - m);
    float a1 = w1 / (w1 + w2), a2 = w2 / (w1 + w2);
    float fv = a1 * e1[d] + a2 * e2[d];
    fused[i * 64 + d] = fv;
    if (eh != nullptr) {
        u16 hv = f2bf(fv);
        eh[i * 64 + d] = hv;
        el[i * 64 + d] = f2bf(fv - bf2f(hv));
    }
    if (alpha != nullptr && d < 2) alpha[i * 2 + d] = (d == 0 ? a1 : a2);
}

// ------------------------------------------------------------- bitpack ----
__global__ void bitpack_kernel(const int* __restrict__ adj,
                               u32* __restrict__ mask, int nwords)
{
    int w = blockIdx.x * 256 + threadIdx.x;
    if (w >= nwords) return;
    const int* src = adj + (size_t)w * 32;
    u32 m = 0;
#pragma unroll
    for (int b = 0; b < 32; b++) m |= (src[b] > 0 ? 1u : 0u) << b;
    mask[w] = m;
}

// ------------------------------------------------------------- driver ----
extern "C" void kernel_launch(void* const* d_in, const int* in_sizes, int n_in,
                              void* d_out, int out_size, void* d_ws, size_t ws_size,
                              hipStream_t stream)
{
    const int N = 4096, DIN = 3000, DINP = 3008, DH = 512, DO = 64;
    const float* x      = (const float*)d_in[0];
    const int*   adjF   = (const int*)d_in[1];
    const int*   adjS   = (const int*)d_in[2];
    const float* We1    = (const float*)d_in[3];
    const float* aE1    = (const float*)d_in[4];
    const float* We2    = (const float*)d_in[5];
    const float* aE2    = (const float*)d_in[6];
    const float* Wd1    = (const float*)d_in[7];
    const float* aD1    = (const float*)d_in[8];
    const float* Wd2    = (const float*)d_in[9];
    const float* aD2    = (const float*)d_in[10];
    const float* Womega = (const float*)d_in[11];
    const float* Uomega = (const float*)d_in[12];

    float* out       = (float*)d_out;
    float* out_emb   = out;                          // [4096,64]
    float* out_recon = out + (size_t)N * DO;         // [4096,3000]
    float* out_corr  = out_recon + (size_t)N * DIN;  // [4096,64]
    float* out_alpha = out_corr + (size_t)N * DO;    // [4096,2]

    char* ws = (char*)d_ws;
    size_t off = 0;
    auto alloc = [&](size_t bytes) {
        size_t o = off; off += (bytes + 255) & ~(size_t)255; return o;
    };
    const size_t o_att   = alloc((size_t)2 * N * N * 2);    // attF|attS, 67 MB
    const size_t o_maskF = alloc((size_t)N * (N / 32) * 4);
    const size_t o_maskS = alloc((size_t)N * (N / 32) * 4);
    const size_t o_s1    = alloc((size_t)2 * N * 4);        // stacked scores
    const size_t o_s2    = alloc((size_t)2 * N * 4);
    const size_t o_wh1   = alloc((size_t)N * DH * 2);       // wh1x / whc1
    const size_t o_h1    = alloc((size_t)2 * N * DH * 2);   // h1f|h1s (c1)
    const size_t o_whd1  = alloc((size_t)N * DH * 2);
    const size_t o_d1    = alloc((size_t)N * DH * 2);
    const size_t o_whd2  = alloc((size_t)N * DIN * 2);      // 24.6 MB
    const size_t o_wh2   = alloc((size_t)2 * N * DO * 2);   // stacked wh2/whc2
    const size_t o_h2    = alloc((size_t)2 * N * DO * 2);   // stacked h2/c2
    const size_t o_t512  = alloc((size_t)DH * N * 2);
    const size_t o_td1   = alloc((size_t)DH * N * 2);
    const size_t o_td2   = alloc((size_t)DIN * N * 2);      // 24.6 MB
    const size_t o_t64a  = alloc((size_t)DO * N * 2);
    const size_t o_t64b  = alloc((size_t)DO * N * 2);
    const size_t o_xh    = alloc((size_t)N * DINP * 2);     // 24.7 MB
    const size_t o_xl    = alloc((size_t)N * DINP * 2);
    const size_t o_we1th = alloc((size_t)DH * DINP * 2);
    const size_t o_we1tl = alloc((size_t)DH * DINP * 2);
    const size_t o_we2th = alloc((size_t)DO * DH * 2);
    const size_t o_we2tl = alloc((size_t)DO * DH * 2);
    const size_t o_wd1th = alloc((size_t)DH * DO * 2);
    const size_t o_wd1tl = alloc((size_t)DH * DO * 2);
    const size_t o_wd2th = alloc((size_t)DIN * DH * 2);
    const size_t o_wd2tl = alloc((size_t)DIN * DH * 2);
    const size_t o_eh    = alloc((size_t)N * DO * 2);
    const size_t o_el    = alloc((size_t)N * DO * 2);
    const size_t o_skp   = alloc((size_t)8 * 2 * N * DO * 4); // 16.8 MB

    u16* attF   = (u16*)(ws + o_att);
    u16* attS   = attF + (size_t)N * N;
    u32* maskF  = (u32*)(ws + o_maskF);
    u32* maskS  = (u32*)(ws + o_maskS);
    float* s1   = (float*)(ws + o_s1);
    float* s2   = (float*)(ws + o_s2);
    u16* wh1x   = (u16*)(ws + o_wh1);
    u16* whc1   = (u16*)(ws + o_wh1);
    u16* h1     = (u16*)(ws + o_h1);
    u16* whd1   = (u16*)(ws + o_whd1);
    u16* d1b    = (u16*)(ws + o_d1);
    u16* whd2   = (u16*)(ws + o_whd2);
    u16* wh2    = (u16*)(ws + o_wh2);
    u16* h2     = (u16*)(ws + o_h2);
    u16* h2f    = h2;
    u16* h2s    = h2 + (size_t)N * DO;
    u16* t512   = (u16*)(ws + o_t512);
    u16* td1    = (u16*)(ws + o_td1);
    u16* td2    = (u16*)(ws + o_td2);
    u16* t64a   = (u16*)(ws + o_t64a);
    u16* t64b   = (u16*)(ws + o_t64b);
    u16* xh     = (u16*)(ws + o_xh);
    u16* xl     = (u16*)(ws + o_xl);
    u16* we1th  = (u16*)(ws + o_we1th);
    u16* we1tl  = (u16*)(ws + o_we1tl);
    u16* we2th  = (u16*)(ws + o_we2th);
    u16* we2tl  = (u16*)(ws + o_we2tl);
    u16* wd1th  = (u16*)(ws + o_wd1th);
    u16* wd1tl  = (u16*)(ws + o_wd1tl);
    u16* wd2th  = (u16*)(ws + o_wd2th);
    u16* wd2tl  = (u16*)(ws + o_wd2tl);
    u16* eh     = (u16*)(ws + o_eh);
    u16* el     = (u16*)(ws + o_el);
    float* skp  = (float*)(ws + o_skp);

    auto grid64 = [](int M, int Nn) { return dim3((Nn + 63) / 64, (M + 127) / 128); };
    auto tr = [&](const u16* src, u16* dst, int R, int C) {
        tr_kernel<<<dim3((C + 31) / 32, (R + 31) / 32), 256, 0, stream>>>(src, dst, R, C);
    };
    auto scores = [&](const u16* Wh, int ld, int F, const float* a) {
        scores_kernel<<<N, 256, 0, stream>>>(Wh, ld, F, a, s1, s2);
    };
    // stacked layer-2 macro: wh2 = A(M=2N) @ We2 (split-K) -> skredTS ->
    // att2 -> dual-B split-K att-GEMM -> skred(ELU) -> h2out (stacked)
    auto layer2 = [&](const u16* Astacked, u16* wh2buf, u16* h2out) {
        tgemm2<false, true><<<dim3(1, 64, 8), 256, 0, stream>>>(
            Astacked, nullptr, we2th, we2tl, skp, 2 * N, DO, DH, 64);
        skredTS_kernel<<<2 * N / 64, 256, 0, stream>>>(
            skp, aE2, wh2buf, t64a, t64b, s1, s2, N, 8);
        att2_kernel<<<2 * N, 256, 0, stream>>>(
            maskF, maskS, s1, s2, N, attF, attS, N);
        tgemm_skd<<<dim3(1, 64, 8), 256, 0, stream>>>(
            attF, t64a, t64b, skp, 2 * N, N, DO, N, 512);
        skred_kernel<true><<<(2 * N * DO + 255) / 256, 256, 0, stream>>>(
            skp, h2out, 2 * N * DO, 8);
    };

    // ---- prep ----
    bitpack_kernel<<<(N * (N / 32) + 255) / 256, 256, 0, stream>>>(adjF, maskF, N * (N / 32));
    bitpack_kernel<<<(N * (N / 32) + 255) / 256, 256, 0, stream>>>(adjS, maskS, N * (N / 32));
    splitA_kernel<<<dim3((DINP + 255) / 256, N), 256, 0, stream>>>(x, xh, xl, DIN, DINP);
    splitBT_kernel<<<dim3((DH + 31) / 32, (DINP + 31) / 32), 256, 0, stream>>>(We1, we1th, we1tl, DIN, DH, DINP);
    splitBT_kernel<<<dim3((DO + 31) / 32, (DH + 31) / 32), 256, 0, stream>>>(We2, we2th, we2tl, DH, DO, DH);
    splitBT_kernel<<<dim3((DH + 31) / 32, (DO + 31) / 32), 256, 0, stream>>>(Wd1, wd1th, wd1tl, DO, DH, DO);
    splitBT_kernel<<<dim3((DIN + 31) / 32, (DH + 31) / 32), 256, 0, stream>>>(Wd2, wd2th, wd2tl, DH, DIN, DH);

    // ---- encoder layer 1 ----
    tgemm2<true, false><<<grid64(N, DH), 256, 0, stream>>>(
        xh, xl, we1th, we1tl, wh1x, N, DH, DINP, DINP);
    tr(wh1x, t512, N, DH);
    scores(wh1x, DH, DH, aE1);
    att2_kernel<<<2 * N, 256, 0, stream>>>(maskF, maskS, s1, s2, 0, attF, attS, N);
    tgemm<true, false, false><<<grid64(2 * N, DH), 256, 0, stream>>>(
        attF, t512, h1, 2 * N, DH, N, nullptr, nullptr, 0);   // h1f|h1s stacked

    // ---- encoder layer 2 (stacked) ----
    layer2(h1, wh2, h2);

    // ---- fuse -> emb_latent + alpha + eh/el split ----
    fuse_kernel<<<N, 64, 0, stream>>>(h2f, h2s, Womega, Uomega, out_emb, out_alpha, eh, el);

    // ---- decoder layer 1 (spatial adj) ----
    tgemm2<true, false><<<grid64(N, DH), 256, 0, stream>>>(
        eh, el, wd1th, wd1tl, whd1, N, DH, DO, DO);
    tr(whd1, td1, N, DH);
    scores(whd1, DH, DH, aD1);
    att_kernel<<<N, 256, 0, stream>>>(maskS, s1, s2, attS, N);
    tgemm<true, false, false><<<grid64(N, DH), 256, 0, stream>>>(
        attS, td1, d1b, N, DH, N, nullptr, nullptr, 0);

    // ---- decoder layer 2 (spatial adj); recon f32 + hi/lo split ----
    tgemm2<false, false><<<grid64(N, DIN), 256, 0, stream>>>(
        d1b, nullptr, wd2th, wd2tl, whd2, N, DIN, DH, DH);
    tr(whd2, td2, N, DIN);
    scores(whd2, DIN, DIN, aD2);
    att_kernel<<<N, 256, 0, stream>>>(maskS, s1, s2, attS, N);
    tgemm<true, true, true><<<grid64(N, DIN), 256, 0, stream>>>(
        attS, td2, out_recon, N, DIN, N, xh, xl, DINP);

    // ---- corr encoder layer 1 (A = recon split in xh/xl) ----
    tgemm2<true, false><<<grid64(N, DH), 256, 0, stream>>>(
        xh, xl, we1th, we1tl, whc1, N, DH, DINP, DINP);
    tr(whc1, t512, N, DH);
    scores(whc1, DH, DH, aE1);
    att2_kernel<<<2 * N, 256, 0, stream>>>(maskF, maskS, s1, s2, 0, attF, attS, N);
    tgemm<true, false, false><<<grid64(2 * N, DH), 256, 0, stream>>>(
        attF, t512, h1, 2 * N, DH, N, nullptr, nullptr, 0);   // c1f|c1s stacked

    // ---- corr encoder layer 2 (stacked) ----
    layer2(h1, wh2, h2);

    // ---- fuse -> corr ----
    fuse_kernel<<<N, 64, 0, stream>>>(h2f, h2s, Womega, Uomega, out_corr, nullptr, nullptr, nullptr);
}

// Round 11
// 972.643 us; speedup vs baseline: 1.2749x; 1.0199x over previous
//
#include <hip/hip_runtime.h>
#include <hip/hip_bf16.h>
#include <math.h>

using u16 = unsigned short;
using u32 = unsigned int;

typedef __attribute__((ext_vector_type(8))) short s8v;    // 8 x bf16 bits (4 VGPRs)
typedef __attribute__((ext_vector_type(4))) short s4v;    // 4 x bf16 bits (8B store)
typedef __attribute__((ext_vector_type(4))) float f4v;    // MFMA acc

__device__ __forceinline__ float bf2f(u16 u) {
    u32 x = ((u32)u) << 16;
    return __builtin_bit_cast(float, x);
}
__device__ __forceinline__ u16 f2bf(float f) {
    u32 x = __builtin_bit_cast(u32, f);
    x += 0x7fffu + ((x >> 16) & 1u);
    return (u16)(x >> 16);
}

__device__ __forceinline__ f4v mfma_bf16(s8v a, s8v b, f4v c) {
    return __builtin_amdgcn_mfma_f32_16x16x32_bf16(a, b, c, 0, 0, 0);
}

#define GLL(srcp, dstp) __builtin_amdgcn_global_load_lds( \
    (const __attribute__((address_space(1))) void*)(srcp), \
    (__attribute__((address_space(3))) void*)(dstp), 16, 0, 0)

// Bijective XCD swizzle (m204): contiguous j-chunks per XCD, x-fastest within.
__device__ __forceinline__ void xcd_swz(int& bx, int& by, int& bz) {
    const int nx = gridDim.x, ny = gridDim.y;
    const int total = nx * ny * gridDim.z;
    int i = (bz * ny + by) * nx + bx;
    const int q = total >> 3, r = total & 7;
    const int xcd = i & 7, k = i >> 3;
    int j = ((xcd < r) ? xcd * (q + 1) : r * (q + 1) + (xcd - r) * q) + k;
    bx = j % nx; j /= nx;
    by = j % ny;
    bz = j / ny;
}

// ------------------------------------------------------------- tgemm ----
// att-GEMM: C[M,N] = A[M,K] @ B[K,N], A bf16 [M,K], Bt[N,K] bf16.
// global_load_lds w=16, linear LDS + XOR chunk swizzle (chunk^=(row&7)),
// 2-phase double-buffer. M%128==0, K%64==0; N arbitrary.
// OUT_SPLIT (with OUT_F32): also writes bf16 hi/lo at stride Cp.
template<bool DO_ELU, bool OUT_F32, bool OUT_SPLIT>
__global__ __launch_bounds__(256) void tgemm(
    const u16* __restrict__ A, const u16* __restrict__ Bt,
    void* __restrict__ Cv, int M, int N, int K,
    u16* __restrict__ Sh, u16* __restrict__ Sl, int Cp)
{
    constexpr int BM = 128, BN = 64, BK = 64;
    __shared__ __align__(16) u16 As[2][BM * BK];
    __shared__ __align__(16) u16 Bs[2][BN * BK];

    int bx = blockIdx.x, by = blockIdx.y, bz = blockIdx.z;
    xcd_swz(bx, by, bz);
    const int bm0 = by * BM, bn0 = bx * BN;
    const int tid = threadIdx.x;
    const int lane = tid & 63;
    const int wave = tid >> 6;
    const int wr = wave >> 1, wc = wave & 1;
    const int lr = lane & 15;
    const int srow = lane >> 3, schk = lane & 7;

    f4v acc[4][2] = {};

    auto stage = [&](int buf, int k0) {
#pragma unroll
        for (int ci = 0; ci < 4; ci++) {
            const int r8 = (wave * 4 + ci) * 8;
            const int row = r8 + srow;
            const int gchk = schk ^ (row & 7);
            GLL(A + (size_t)(bm0 + row) * K + k0 + gchk * 8, &As[buf][r8 * 64]);
        }
#pragma unroll
        for (int ci = 0; ci < 2; ci++) {
            const int r8 = (wave * 2 + ci) * 8;
            const int row = r8 + srow;
            int gn = bn0 + row;
            if (gn >= N) gn = N - 1;
            const int gchk = schk ^ (row & 7);
            GLL(Bt + (size_t)gn * K + k0 + gchk * 8, &Bs[buf][r8 * 64]);
        }
    };

    stage(0, 0);
    __syncthreads();
    int cur = 0;
    for (int k0 = 0; k0 < K; k0 += BK) {
        if (k0 + BK < K) stage(cur ^ 1, k0 + BK);
#pragma unroll
        for (int kk = 0; kk < 2; kk++) {
            const int cbase = (lane >> 4) + kk * 4;
            s8v a[4], b[2];
#pragma unroll
            for (int m = 0; m < 4; m++) {
                const int row = wr * 64 + m * 16 + lr;
                a[m] = *(const s8v*)&As[cur][row * 64 + (cbase ^ (row & 7)) * 8];
            }
#pragma unroll
            for (int n = 0; n < 2; n++) {
                const int row = wc * 32 + n * 16 + lr;
                b[n] = *(const s8v*)&Bs[cur][row * 64 + (cbase ^ (row & 7)) * 8];
            }
#pragma unroll
            for (int m = 0; m < 4; m++)
#pragma unroll
                for (int n = 0; n < 2; n++)
                    acc[m][n] = mfma_bf16(a[m], b[n], acc[m][n]);
        }
        __syncthreads();
        cur ^= 1;
    }

#pragma unroll
    for (int m = 0; m < 4; m++)
#pragma unroll
        for (int n = 0; n < 2; n++)
#pragma unroll
            for (int i = 0; i < 4; i++) {
                int gm = bm0 + wr * 64 + m * 16 + (lane >> 4) * 4 + i;
                int gn = bn0 + wc * 32 + n * 16 + lr;
                if (gm < M && gn < N) {
                    float val = acc[m][n][i];
                    if (DO_ELU) val = val > 0.f ? val : expm1f(val);
                    if (OUT_F32) {
                        ((float*)Cv)[(size_t)gm * N + gn] = val;
                        if (OUT_SPLIT) {
                            u16 hv = f2bf(val);
                            Sh[(size_t)gm * Cp + gn] = hv;
                            Sl[(size_t)gm * Cp + gn] = f2bf(val - bf2f(hv));
                        }
                    } else {
                        ((u16*)Cv)[(size_t)gm * N + gn] = f2bf(val);
                    }
                }
            }
}

// ---------------------------------------------------------- tgemm_skd ----
// Dual-B stacked split-K att-GEMM (N=64): rows < Mh use BtA, else BtB.
// grid (1, M/128, z); f32 partials P[z][M][N].
__global__ __launch_bounds__(256) void tgemm_skd(
    const u16* __restrict__ A, const u16* __restrict__ BtA,
    const u16* __restrict__ BtB, float* __restrict__ P,
    int M, int Mh, int N, int K, int KS)
{
    constexpr int BM = 128, BN = 64, BK = 64;
    __shared__ __align__(16) u16 As[2][BM * BK];
    __shared__ __align__(16) u16 Bs[2][BN * BK];

    int bx = blockIdx.x, by = blockIdx.y, kz = blockIdx.z;
    xcd_swz(bx, by, kz);
    const int bm0 = by * BM, bn0 = bx * BN;
    const u16* Bt = (bm0 < Mh) ? BtA : BtB;
    const int tid = threadIdx.x;
    const int lane = tid & 63;
    const int wave = tid >> 6;
    const int wr = wave >> 1, wc = wave & 1;
    const int lr = lane & 15;
    const int srow = lane >> 3, schk = lane & 7;

    f4v acc[4][2] = {};

    auto stage = [&](int buf, int k0) {
#pragma unroll
        for (int ci = 0; ci < 4; ci++) {
            const int r8 = (wave * 4 + ci) * 8;
            const int row = r8 + srow;
            const int gchk = schk ^ (row & 7);
            GLL(A + (size_t)(bm0 + row) * K + k0 + gchk * 8, &As[buf][r8 * 64]);
        }
#pragma unroll
        for (int ci = 0; ci < 2; ci++) {
            const int r8 = (wave * 2 + ci) * 8;
            const int row = r8 + srow;
            int gn = bn0 + row;
            if (gn >= N) gn = N - 1;
            const int gchk = schk ^ (row & 7);
            GLL(Bt + (size_t)gn * K + k0 + gchk * 8, &Bs[buf][r8 * 64]);
        }
    };

    const int kbeg = kz * KS, kend = kbeg + KS;
    stage(0, kbeg);
    __syncthreads();
    int cur = 0;
    for (int k0 = kbeg; k0 < kend; k0 += BK) {
        if (k0 + BK < kend) stage(cur ^ 1, k0 + BK);
#pragma unroll
        for (int kk = 0; kk < 2; kk++) {
            const int cbase = (lane >> 4) + kk * 4;
            s8v a[4], b[2];
#pragma unroll
            for (int m = 0; m < 4; m++) {
                const int row = wr * 64 + m * 16 + lr;
                a[m] = *(const s8v*)&As[cur][row * 64 + (cbase ^ (row & 7)) * 8];
            }
#pragma unroll
            for (int n = 0; n < 2; n++) {
                const int row = wc * 32 + n * 16 + lr;
                b[n] = *(const s8v*)&Bs[cur][row * 64 + (cbase ^ (row & 7)) * 8];
            }
#pragma unroll
            for (int m = 0; m < 4; m++)
#pragma unroll
                for (int n = 0; n < 2; n++)
                    acc[m][n] = mfma_bf16(a[m], b[n], acc[m][n]);
        }
        __syncthreads();
        cur ^= 1;
    }

    float* Pz = P + (size_t)kz * M * N;
#pragma unroll
    for (int m = 0; m < 4; m++)
#pragma unroll
        for (int n = 0; n < 2; n++)
#pragma unroll
            for (int i = 0; i < 4; i++) {
                int gm = bm0 + wr * 64 + m * 16 + (lane >> 4) * 4 + i;
                int gn = bn0 + wc * 32 + n * 16 + lr;
                if (gm < M && gn < N)
                    Pz[(size_t)gm * N + gn] = acc[m][n][i];
            }
}

// ------------------------------------------------------------- tgemm2 ----
// Weight-GEMM (pre-split bf16 hi/lo), BK=32, 2-phase double-buffer.
// Chunk swizzle (row&3)^((row>>2)&1) keeps ds_read_b128 <=2-way.
// SK: grid.z slices K, f32 partials to Cv.
// TROUT: epilogue also writes transposed bf16 Ct[gn*M + gm] (bit-identical
// to a separate transpose pass; kills the tr_kernel launch + wh re-read).
template<bool ASP, bool SK, bool TROUT>
__global__ __launch_bounds__(256) void tgemm2(
    const u16* __restrict__ A0, const u16* __restrict__ A1,
    const u16* __restrict__ Bt0, const u16* __restrict__ Bt1,
    void* __restrict__ Cv, int M, int N, int K, int KS,
    u16* __restrict__ Ct)
{
    constexpr int BM = 128, BN = 64, BK = 32;
    __shared__ __align__(16) u16 As0[2][BM * BK];
    __shared__ __align__(16) u16 As1[ASP ? 2 : 1][ASP ? BM * BK : 8];
    __shared__ __align__(16) u16 Bs0[2][BN * BK];
    __shared__ __align__(16) u16 Bs1[2][BN * BK];

    int bx = blockIdx.x, by = blockIdx.y, kz = blockIdx.z;
    xcd_swz(bx, by, kz);
    const int bm0 = by * BM, bn0 = bx * BN;
    const int tid = threadIdx.x;
    const int lane = tid & 63;
    const int wave = tid >> 6;
    const int wr = wave >> 1, wc = wave & 1;
    const int lr = lane & 15;
    const int srow = lane >> 2;      // 16 rows per 1KB wave-chunk
    const int schk = lane & 3;       // 4 chunks per 64B row

    auto swzr = [](int row) { return (row & 3) ^ ((row >> 2) & 1); };

    f4v acc[4][2] = {};

    auto stage = [&](int buf, int k0) {
#pragma unroll
        for (int ci = 0; ci < 2; ci++) {
            const int r16 = (wave * 2 + ci) * 16;
            const int row = r16 + srow;
            const int gchk = schk ^ swzr(row);
            const size_t goff = (size_t)(bm0 + row) * K + k0 + gchk * 8;
            GLL(A0 + goff, &As0[buf][r16 * 32]);
            if constexpr (ASP) GLL(A1 + goff, &As1[buf][r16 * 32]);
        }
        {
            const int r16 = wave * 16;
            const int row = r16 + srow;
            int gn = bn0 + row;
            if (gn >= N) gn = N - 1;
            const int gchk = schk ^ swzr(row);
            const size_t goff = (size_t)gn * K + k0 + gchk * 8;
            GLL(Bt0 + goff, &Bs0[buf][r16 * 32]);
            GLL(Bt1 + goff, &Bs1[buf][r16 * 32]);
        }
    };

    const int kbeg = SK ? kz * KS : 0;
    const int kend = SK ? kbeg + KS : K;
    stage(0, kbeg);
    __syncthreads();
    int cur = 0;
    for (int k0 = kbeg; k0 < kend; k0 += BK) {
        if (k0 + BK < kend) stage(cur ^ 1, k0 + BK);
        {
            const int cbase = lane >> 4;     // 0..3
            s8v a0[4], a1[ASP ? 4 : 1], b0[2], b1[2];
#pragma unroll
            for (int m = 0; m < 4; m++) {
                const int row = wr * 64 + m * 16 + lr;
                const int o = row * 32 + (cbase ^ swzr(row)) * 8;
                a0[m] = *(const s8v*)&As0[cur][o];
                if constexpr (ASP) a1[m] = *(const s8v*)&As1[cur][o];
            }
#pragma unroll
            for (int n = 0; n < 2; n++) {
                const int row = wc * 32 + n * 16 + lr;
                const int o = row * 32 + (cbase ^ swzr(row)) * 8;
                b0[n] = *(const s8v*)&Bs0[cur][o];
                b1[n] = *(const s8v*)&Bs1[cur][o];
            }
#pragma unroll
            for (int m = 0; m < 4; m++)
#pragma unroll
                for (int n = 0; n < 2; n++) {
                    acc[m][n] = mfma_bf16(a0[m], b0[n], acc[m][n]);
                    acc[m][n] = mfma_bf16(a0[m], b1[n], acc[m][n]);
                    if constexpr (ASP) acc[m][n] = mfma_bf16(a1[m], b0[n], acc[m][n]);
                }
        }
        __syncthreads();
        cur ^= 1;
    }

#pragma unroll
    for (int m = 0; m < 4; m++)
#pragma unroll
        for (int n = 0; n < 2; n++) {
            const int gm0 = bm0 + wr * 64 + m * 16 + (lane >> 4) * 4;
            const int gn = bn0 + wc * 32 + n * 16 + lr;
            u16 q[4];
#pragma unroll
            for (int i = 0; i < 4; i++) {
                int gm = gm0 + i;
                if (gm < M && gn < N) {
                    if (SK) {
                        ((float*)Cv)[(size_t)kz * M * N + (size_t)gm * N + gn] = acc[m][n][i];
                    } else {
                        u16 hv = f2bf(acc[m][n][i]);
                        ((u16*)Cv)[(size_t)gm * N + gn] = hv;
                        q[i] = hv;
                    }
                }
            }
            if constexpr (TROUT) {
                if (gn < N && gm0 + 3 < M)
                    *(s4v*)&Ct[(size_t)gn * M + gm0] = *(const s4v*)q;
            }
        }
}

// ------------------------------------------------------------- skredTS ----
// Fused: split-K partial sum -> transposed bf16 [64][N] halves + scores dot
// (s1,s2 stacked). 64 rows/block; thread = (row, 16-col group).
__global__ __launch_bounds__(256) void skredTS_kernel(
    const float* __restrict__ P, const float* __restrict__ a,
    u16* __restrict__ tA, u16* __restrict__ tB,
    float* __restrict__ s1, float* __restrict__ s2, int n, int sk)
{
    __shared__ u16 lds[64][72];
    const int rowbase = blockIdx.x * 64;
    const int t = threadIdx.x;
    const int rl = t >> 2, cg = t & 3;
    const int row = rowbase + rl;
    const size_t M2 = (size_t)2 * n;

    float v[16];
#pragma unroll
    for (int k = 0; k < 16; k++) v[k] = 0.f;
    for (int z = 0; z < sk; z++) {
        const float4* p = (const float4*)&P[((size_t)z * M2 + row) * 64 + cg * 16];
#pragma unroll
        for (int q = 0; q < 4; q++) {
            float4 x = p[q];
            v[q * 4 + 0] += x.x; v[q * 4 + 1] += x.y;
            v[q * 4 + 2] += x.z; v[q * 4 + 3] += x.w;
        }
    }
    u16 w[16];
    float p1 = 0.f, p2 = 0.f;
#pragma unroll
    for (int k = 0; k < 16; k++) {
        w[k] = f2bf(v[k]);
        float vr = bf2f(w[k]);
        int f = cg * 16 + k;
        p1 += vr * a[f];
        p2 += vr * a[64 + f];
    }
    *(s8v*)&lds[rl][cg * 16]     = *(s8v*)&w[0];
    *(s8v*)&lds[rl][cg * 16 + 8] = *(s8v*)&w[8];

    p1 += __shfl_down(p1, 1); p1 += __shfl_down(p1, 2);
    p2 += __shfl_down(p2, 1); p2 += __shfl_down(p2, 2);
    if (cg == 0) { s1[row] = p1; s2[row] = p2; }
    __syncthreads();

    // transpose out: thread -> col rl, rows cg*16..+16
    const bool hb = rowbase >= n;
    u16* tX = hb ? tB : tA;
    const int grow = rowbase - (hb ? n : 0);
    u16 o[16];
#pragma unroll
    for (int k = 0; k < 16; k++) o[k] = lds[cg * 16 + k][rl];
    *(s8v*)&tX[(size_t)rl * n + grow + cg * 16]     = *(s8v*)&o[0];
    *(s8v*)&tX[(size_t)rl * n + grow + cg * 16 + 8] = *(s8v*)&o[8];
}

// -------------------------------------------------------------- splits ----
__global__ __launch_bounds__(256) void splitA_kernel(
    const float* __restrict__ src, u16* __restrict__ hi, u16* __restrict__ lo,
    int C, int Cp)
{
    int r = blockIdx.y;
    int c = blockIdx.x * 256 + threadIdx.x;
    if (c >= Cp) return;
    float v = (c < C) ? src[(size_t)r * C + c] : 0.f;
    u16 h = f2bf(v);
    hi[(size_t)r * Cp + c] = h;
    lo[(size_t)r * Cp + c] = f2bf(v - bf2f(h));
}

__global__ __launch_bounds__(256) void splitBT_kernel(
    const float* __restrict__ src, u16* __restrict__ hi, u16* __restrict__ lo,
    int R, int C, int Rp)
{
    __shared__ float t[32][33];
    const int r0 = blockIdx.y * 32, c0 = blockIdx.x * 32;
    const int tr = threadIdx.x >> 5, tc = threadIdx.x & 31;
#pragma unroll
    for (int i = 0; i < 4; i++) {
        int r = r0 + tr + i * 8, c = c0 + tc;
        t[tr + i * 8][tc] = (r < R && c < C) ? src[(size_t)r * C + c] : 0.f;
    }
    __syncthreads();
#pragma unroll
    for (int i = 0; i < 4; i++) {
        int c = c0 + tr + i * 8, r = r0 + tc;
        if (c < C && r < Rp) {
            float v = t[tc][tr + i * 8];
            u16 h = f2bf(v);
            hi[(size_t)c * Rp + r] = h;
            lo[(size_t)c * Rp + r] = f2bf(v - bf2f(h));
        }
    }
}

// ------------------------------------------------------------- reduce ----
__device__ __forceinline__ float block_sum4(float v, float* red) {
#pragma unroll
    for (int off = 32; off; off >>= 1) v += __shfl_down(v, off);
    int w = threadIdx.x >> 6;
    if ((threadIdx.x & 63) == 0) red[w] = v;
    __syncthreads();
    float r = red[0] + red[1] + red[2] + red[3];
    __syncthreads();
    return r;
}
__device__ __forceinline__ float block_max4(float v, float* red) {
#pragma unroll
    for (int off = 32; off; off >>= 1) v = fmaxf(v, __shfl_down(v, off));
    int w = threadIdx.x >> 6;
    if ((threadIdx.x & 63) == 0) red[w] = v;
    __syncthreads();
    float r = fmaxf(fmaxf(red[0], red[1]), fmaxf(red[2], red[3]));
    __syncthreads();
    return r;
}

// ------------------------------------------------------------- scores ----
__global__ __launch_bounds__(256) void scores_kernel(
    const u16* __restrict__ Wh, int ld, int F, const float* __restrict__ a,
    float* __restrict__ s1, float* __restrict__ s2)
{
    __shared__ float red[4];
    int i = blockIdx.x, tid = threadIdx.x;
    float acc1 = 0.f, acc2 = 0.f;
    for (int f = tid; f < F; f += 256) {
        float w = bf2f(Wh[(size_t)i * ld + f]);
        acc1 += w * a[f];
        acc2 += w * a[F + f];
    }
    acc1 = block_sum4(acc1, red);
    acc2 = block_sum4(acc2, red);
    if (tid == 0) { s1[i] = acc1; s2[i] = acc2; }
}

// ---------------------------------------------------------------- att ----
__device__ __forceinline__ void att_row(
    const u32* mask, const float* s1, const float* s2, int soff,
    u16* att, int i, int n, float* red)
{
    int tid = threadIdx.x;
    float s1i = s1[soff + i];
    int j0 = tid * 16;
    u32 w = mask[(size_t)i * (n >> 5) + (j0 >> 5)];
    u32 bits = (j0 & 16) ? (w >> 16) : (w & 0xFFFFu);

    float e[16];
    float mx = -3.0e38f;
#pragma unroll
    for (int t = 0; t < 16; t++) {
        float x = s1i + s2[soff + j0 + t];
        x = x > 0.f ? x : 0.2f * x;
        e[t] = x;
        if ((bits >> t) & 1u) mx = fmaxf(mx, x);
    }
    mx = block_max4(mx, red);

    float sum = 0.f;
#pragma unroll
    for (int t = 0; t < 16; t++) {
        float pv = ((bits >> t) & 1u) ? expf(e[t] - mx) : 0.f;
        e[t] = pv;
        sum += pv;
    }
    sum = block_sum4(sum, red);
    float rinv = sum > 0.f ? 1.f / sum : 0.f;
#pragma unroll
    for (int t = 0; t < 16; t++)
        att[(size_t)i * n + j0 + t] = f2bf(e[t] * rinv);
}

__global__ __launch_bounds__(256) void att_kernel(
    const u32* __restrict__ mask, const float* __restrict__ s1,
    const float* __restrict__ s2, u16* __restrict__ att, int n)
{
    __shared__ float red[4];
    att_row(mask, s1, s2, 0, att, blockIdx.x, n, red);
}

// dual: blocks [0,n) -> maskA/attA (soff 0); [n,2n) -> maskB/attB (soff offB)
__global__ __launch_bounds__(256) void att2_kernel(
    const u32* __restrict__ maskA, const u32* __restrict__ maskB,
    const float* __restrict__ s1, const float* __restrict__ s2, int offB,
    u16* __restrict__ attA, u16* __restrict__ attB, int n)
{
    __shared__ float red[4];
    int b = blockIdx.x;
    if (b < n) att_row(maskA, s1, s2, 0, attA, b, n, red);
    else      att_row(maskB, s1, s2, offB, attB, b - n, n, red);
}

// ------------------------------------------------------------- fuse_sk ----
// Fused skred(ELU)+fuse: reads split-K partials P[z][2n][64] (rows i and
// n+i are the two views), reduces+ELU in f32, then AttentionLayer fuse.
__global__ __launch_bounds__(64) void fuse_sk_kernel(
    const float* __restrict__ P, const float* __restrict__ W,
    const float* __restrict__ U, float* __restrict__ fused,
    float* __restrict__ alpha, u16* __restrict__ eh, u16* __restrict__ el,
    int n, int sk)
{
    __shared__ float e1[64], e2[64];
    int i = blockIdx.x, d = threadIdx.x;
    const size_t M2 = (size_t)2 * n;
    float sf = 0.f, ss = 0.f;
    for (int z = 0; z < sk; z++) {
        sf += P[((size_t)z * M2 + i) * 64 + d];
        ss += P[((size_t)z * M2 + n + i) * 64 + d];
    }
    sf = sf > 0.f ? sf : expm1f(sf);
    ss = ss > 0.f ? ss : expm1f(ss);
    e1[d] = sf;
    e2[d] = ss;
    __syncthreads();
    float v1 = 0.f, v2 = 0.f;
#pragma unroll 8
    for (int f = 0; f < 64; f++) {
        float w = W[f * 64 + d];
        v1 += e1[f] * w;
        v2 += e2[f] * w;
    }
    v1 = tanhf(v1); v2 = tanhf(v2);
    float u = U[d];
    float p1 = v1 * u, p2 = v2 * u;
#pragma unroll
    for (int off = 32; off; off >>= 1) {
        p1 += __shfl_down(p1, off);
        p2 += __shfl_down(p2, off);
    }
    p1 = __shfl(p1, 0); p2 = __shfl(p2, 0);
    float m = fmaxf(p1, p2);
    float w1 = expf(p1 - m), w2 = expf(p2 - m);
    float a1 = w1 / (w1 + w2), a2 = w2 / (w1 + w2);
    float fv = a1 * e1[d] + a2 * e2[d];
    fused[i * 64 + d] = fv;
    if (eh != nullptr) {
        u16 hv = f2bf(fv);
        eh[i * 64 + d] = hv;
        el[i * 64 + d] = f2bf(fv - bf2f(hv));
    }
    if (alpha != nullptr && d < 2) alpha[i * 2 + d] = (d == 0 ? a1 : a2);
}

// ------------------------------------------------------------- bitpack ----
__global__ void bitpack_kernel(const int* __restrict__ adj,
                               u32* __restrict__ mask, int nwords)
{
    int w = blockIdx.x * 256 + threadIdx.x;
    if (w >= nwords) return;
    const int* src = adj + (size_t)w * 32;
    u32 m = 0;
#pragma unroll
    for (int b = 0; b < 32; b++) m |= (src[b] > 0 ? 1u : 0u) << b;
    mask[w] = m;
}

// ------------------------------------------------------------- driver ----
extern "C" void kernel_launch(void* const* d_in, const int* in_sizes, int n_in,
                              void* d_out, int out_size, void* d_ws, size_t ws_size,
                              hipStream_t stream)
{
    const int N = 4096, DIN = 3000, DINP = 3008, DH = 512, DO = 64;
    const float* x      = (const float*)d_in[0];
    const int*   adjF   = (const int*)d_in[1];
    const int*   adjS   = (const int*)d_in[2];
    const float* We1    = (const float*)d_in[3];
    const float* aE1    = (const float*)d_in[4];
    const float* We2    = (const float*)d_in[5];
    const float* aE2    = (const float*)d_in[6];
    const float* Wd1    = (const float*)d_in[7];
    const float* aD1    = (const float*)d_in[8];
    const float* Wd2    = (const float*)d_in[9];
    const float* aD2    = (const float*)d_in[10];
    const float* Womega = (const float*)d_in[11];
    const float* Uomega = (const float*)d_in[12];

    float* out       = (float*)d_out;
    float* out_emb   = out;                          // [4096,64]
    float* out_recon = out + (size_t)N * DO;         // [4096,3000]
    float* out_corr  = out_recon + (size_t)N * DIN;  // [4096,64]
    float* out_alpha = out_corr + (size_t)N * DO;    // [4096,2]

    char* ws = (char*)d_ws;
    size_t off = 0;
    auto alloc = [&](size_t bytes) {
        size_t o = off; off += (bytes + 255) & ~(size_t)255; return o;
    };
    const size_t o_att   = alloc((size_t)2 * N * N * 2);    // attF|attS, 67 MB
    const size_t o_maskF = alloc((size_t)N * (N / 32) * 4);
    const size_t o_maskS = alloc((size_t)N * (N / 32) * 4);
    const size_t o_s1    = alloc((size_t)2 * N * 4);        // stacked scores
    const size_t o_s2    = alloc((size_t)2 * N * 4);
    const size_t o_wh1   = alloc((size_t)N * DH * 2);       // wh1x / whc1
    const size_t o_h1    = alloc((size_t)2 * N * DH * 2);   // h1f|h1s (c1)
    const size_t o_whd1  = alloc((size_t)N * DH * 2);
    const size_t o_d1    = alloc((size_t)N * DH * 2);
    const size_t o_whd2  = alloc((size_t)N * DIN * 2);      // 24.6 MB
    const size_t o_t512  = alloc((size_t)DH * N * 2);
    const size_t o_td1   = alloc((size_t)DH * N * 2);
    const size_t o_td2   = alloc((size_t)DIN * N * 2);      // 24.6 MB
    const size_t o_t64a  = alloc((size_t)DO * N * 2);
    const size_t o_t64b  = alloc((size_t)DO * N * 2);
    const size_t o_xh    = alloc((size_t)N * DINP * 2);     // 24.7 MB
    const size_t o_xl    = alloc((size_t)N * DINP * 2);
    const size_t o_we1th = alloc((size_t)DH * DINP * 2);
    const size_t o_we1tl = alloc((size_t)DH * DINP * 2);
    const size_t o_we2th = alloc((size_t)DO * DH * 2);
    const size_t o_we2tl = alloc((size_t)DO * DH * 2);
    const size_t o_wd1th = alloc((size_t)DH * DO * 2);
    const size_t o_wd1tl = alloc((size_t)DH * DO * 2);
    const size_t o_wd2th = alloc((size_t)DIN * DH * 2);
    const size_t o_wd2tl = alloc((size_t)DIN * DH * 2);
    const size_t o_eh    = alloc((size_t)N * DO * 2);
    const size_t o_el    = alloc((size_t)N * DO * 2);
    const size_t o_skp   = alloc((size_t)8 * 2 * N * DO * 4); // 16.8 MB

    u16* attF   = (u16*)(ws + o_att);
    u16* attS   = attF + (size_t)N * N;
    u32* maskF  = (u32*)(ws + o_maskF);
    u32* maskS  = (u32*)(ws + o_maskS);
    float* s1   = (float*)(ws + o_s1);
    float* s2   = (float*)(ws + o_s2);
    u16* wh1x   = (u16*)(ws + o_wh1);
    u16* whc1   = (u16*)(ws + o_wh1);
    u16* h1     = (u16*)(ws + o_h1);
    u16* whd1   = (u16*)(ws + o_whd1);
    u16* d1b    = (u16*)(ws + o_d1);
    u16* whd2   = (u16*)(ws + o_whd2);
    u16* t512   = (u16*)(ws + o_t512);
    u16* td1    = (u16*)(ws + o_td1);
    u16* td2    = (u16*)(ws + o_td2);
    u16* t64a   = (u16*)(ws + o_t64a);
    u16* t64b   = (u16*)(ws + o_t64b);
    u16* xh     = (u16*)(ws + o_xh);
    u16* xl     = (u16*)(ws + o_xl);
    u16* we1th  = (u16*)(ws + o_we1th);
    u16* we1tl  = (u16*)(ws + o_we1tl);
    u16* we2th  = (u16*)(ws + o_we2th);
    u16* we2tl  = (u16*)(ws + o_we2tl);
    u16* wd1th  = (u16*)(ws + o_wd1th);
    u16* wd1tl  = (u16*)(ws + o_wd1tl);
    u16* wd2th  = (u16*)(ws + o_wd2th);
    u16* wd2tl  = (u16*)(ws + o_wd2tl);
    u16* eh     = (u16*)(ws + o_eh);
    u16* el     = (u16*)(ws + o_el);
    float* skp  = (float*)(ws + o_skp);

    auto grid64 = [](int M, int Nn) { return dim3((Nn + 63) / 64, (M + 127) / 128); };
    auto scores = [&](const u16* Wh, int ld, int F, const float* a) {
        scores_kernel<<<N, 256, 0, stream>>>(Wh, ld, F, a, s1, s2);
    };
    // stacked layer-2 macro: wh2 = A(M=2N) @ We2 (split-K) -> skredTS ->
    // att2 -> dual-B split-K att-GEMM; caller finishes with fuse_sk.
    auto layer2 = [&](const u16* Astacked) {
        tgemm2<false, true, false><<<dim3(1, 64, 8), 256, 0, stream>>>(
            Astacked, nullptr, we2th, we2tl, skp, 2 * N, DO, DH, 64, nullptr);
        skredTS_kernel<<<2 * N / 64, 256, 0, stream>>>(
            skp, aE2, t64a, t64b, s1, s2, N, 8);
        att2_kernel<<<2 * N, 256, 0, stream>>>(
            maskF, maskS, s1, s2, N, attF, attS, N);
        tgemm_skd<<<dim3(1, 64, 8), 256, 0, stream>>>(
            attF, t64a, t64b, skp, 2 * N, N, DO, N, 512);
    };

    // ---- prep ----
    bitpack_kernel<<<(N * (N / 32) + 255) / 256, 256, 0, stream>>>(adjF, maskF, N * (N / 32));
    bitpack_kernel<<<(N * (N / 32) + 255) / 256, 256, 0, stream>>>(adjS, maskS, N * (N / 32));
    splitA_kernel<<<dim3((DINP + 255) / 256, N), 256, 0, stream>>>(x, xh, xl, DIN, DINP);
    splitBT_kernel<<<dim3((DH + 31) / 32, (DINP + 31) / 32), 256, 0, stream>>>(We1, we1th, we1tl, DIN, DH, DINP);
    splitBT_kernel<<<dim3((DO + 31) / 32, (DH + 31) / 32), 256, 0, stream>>>(We2, we2th, we2tl, DH, DO, DH);
    splitBT_kernel<<<dim3((DH + 31) / 32, (DO + 31) / 32), 256, 0, stream>>>(Wd1, wd1th, wd1tl, DO, DH, DO);
    splitBT_kernel<<<dim3((DIN + 31) / 32, (DH + 31) / 32), 256, 0, stream>>>(Wd2, wd2th, wd2tl, DH, DIN, DH);

    // ---- encoder layer 1 (TROUT writes wh1x + t512 in one pass) ----
    tgemm2<true, false, true><<<grid64(N, DH), 256, 0, stream>>>(
        xh, xl, we1th, we1tl, wh1x, N, DH, DINP, DINP, t512);
    scores(wh1x, DH, DH, aE1);
    att2_kernel<<<2 * N, 256, 0, stream>>>(maskF, maskS, s1, s2, 0, attF, attS, N);
    tgemm<true, false, false><<<grid64(2 * N, DH), 256, 0, stream>>>(
        attF, t512, h1, 2 * N, DH, N, nullptr, nullptr, 0);   // h1f|h1s stacked

    // ---- encoder layer 2 (stacked) + fuse -> emb_latent + alpha + eh/el ----
    layer2(h1);
    fuse_sk_kernel<<<N, 64, 0, stream>>>(
        skp, Womega, Uomega, out_emb, out_alpha, eh, el, N, 8);

    // ---- decoder layer 1 (spatial adj) ----
    tgemm2<true, false, true><<<grid64(N, DH), 256, 0, stream>>>(
        eh, el, wd1th, wd1tl, whd1, N, DH, DO, DO, td1);
    scores(whd1, DH, DH, aD1);
    att_kernel<<<N, 256, 0, stream>>>(maskS, s1, s2, attS, N);
    tgemm<true, false, false><<<grid64(N, DH), 256, 0, stream>>>(
        attS, td1, d1b, N, DH, N, nullptr, nullptr, 0);

    // ---- decoder layer 2 (spatial adj); recon f32 + hi/lo split ----
    tgemm2<false, false, true><<<grid64(N, DIN), 256, 0, stream>>>(
        d1b, nullptr, wd2th, wd2tl, whd2, N, DIN, DH, DH, td2);
    scores(whd2, DIN, DIN, aD2);
    att_kernel<<<N, 256, 0, stream>>>(maskS, s1, s2, attS, N);
    tgemm<true, true, true><<<grid64(N, DIN), 256, 0, stream>>>(
        attS, td2, out_recon, N, DIN, N, xh, xl, DINP);

    // ---- corr encoder layer 1 (A = recon split in xh/xl) ----
    tgemm2<true, false, true><<<grid64(N, DH), 256, 0, stream>>>(
        xh, xl, we1th, we1tl, whc1, N, DH, DINP, DINP, t512);
    scores(whc1, DH, DH, aE1);
    att2_kernel<<<2 * N, 256, 0, stream>>>(maskF, maskS, s1, s2, 0, attF, attS, N);
    tgemm<true, false, false><<<grid64(2 * N, DH), 256, 0, stream>>>(
        attF, t512, h1, 2 * N, DH, N, nullptr, nullptr, 0);   // c1f|c1s stacked

    // ---- corr encoder layer 2 (stacked) + fuse -> corr ----
    layer2(h1);
    fuse_sk_kernel<<<N, 64, 0, stream>>>(
        skp, Womega, Uomega, out_corr, nullptr, nullptr, nullptr, N, 8);
}